// Round 6
// baseline (196.491 us; speedup 1.0000x reference)
//
#include <hip/hip_runtime.h>
#include <hip/hip_bf16.h>
#include <cstdint>
#include <cstddef>

// Problem constants
#define SEQ   2048
#define HID   2048
#define NH    32
#define NKVH  8
#define HD    64
#define KVDIM (NKVH * HD)   // 512

typedef __bf16 bf16_t;
typedef __bf16 bf16x8 __attribute__((ext_vector_type(8)));
typedef float  f32x4  __attribute__((ext_vector_type(4)));

// log2(10000)/32  (RoPE: theta^(-d/32) = exp2(-d*L))
#define ROPE_L 0.4152410118609203f

#if __has_builtin(__builtin_amdgcn_exp2f)
#define QSCALE 0.18033688011112043f
#define EXPFN(x) __builtin_amdgcn_exp2f(x)
#else
#define QSCALE 0.125f
#define EXPFN(x) __expf(x)
#endif

__device__ __forceinline__ bf16x8 load8(const float* p) {
    const float4 lo = *(const float4*)p;
    const float4 hi = *(const float4*)(p + 4);
    bf16x8 r;
    r[0] = (bf16_t)lo.x; r[1] = (bf16_t)lo.y; r[2] = (bf16_t)lo.z; r[3] = (bf16_t)lo.w;
    r[4] = (bf16_t)hi.x; r[5] = (bf16_t)hi.y; r[6] = (bf16_t)hi.z; r[7] = (bf16_t)hi.w;
    return r;
}

// async global->LDS, 16B per lane; LDS dest = wave-uniform base + lane*16
__device__ __forceinline__ void load_lds16(const bf16_t* g, bf16_t* l) {
    __builtin_amdgcn_global_load_lds((const __attribute__((address_space(1))) void*)g,
                                     (__attribute__((address_space(3))) void*)l,
                                     16, 0, 0);
}

// ---------------------------------------------------------------------------
// One-shot fp32 -> bf16 conversion of all GEMM operands.
// ---------------------------------------------------------------------------
#define NX  (SEQ * HID)          // 4M
#define NWQ (NH * HD * HID)      // 4M
#define NWK (KVDIM * HID)        // 1M
#define NWV (KVDIM * HID)        // 1M
#define NWO (HID * NH * HD)      // 4M
#define NTOT (NX + NWQ + NWK + NWV + NWO)   // 14M

__global__ __launch_bounds__(256) void cvt_all(const float* __restrict__ X,
                                               const float* __restrict__ Wq,
                                               const float* __restrict__ Wk,
                                               const float* __restrict__ Wv,
                                               const float* __restrict__ Wo,
                                               bf16_t* __restrict__ Xb,
                                               bf16_t* __restrict__ Wqb,
                                               bf16_t* __restrict__ Wkb,
                                               bf16_t* __restrict__ Wvb,
                                               bf16_t* __restrict__ Wob)
{
    size_t i = ((size_t)blockIdx.x * 256 + threadIdx.x) * 8;
    if (i >= NTOT) return;
    const size_t E0 = NX, E1 = E0 + NWQ, E2 = E1 + NWK, E3 = E2 + NWV;
    const float* s; bf16_t* d; size_t off;
    if (i < E0)      { s = X;  d = Xb;  off = i; }
    else if (i < E1) { s = Wq; d = Wqb; off = i - E0; }
    else if (i < E2) { s = Wk; d = Wkb; off = i - E1; }
    else if (i < E3) { s = Wv; d = Wvb; off = i - E2; }
    else             { s = Wo; d = Wob; off = i - E3; }
    *(bf16x8*)(d + off) = load8(s + off);
}

// ---------------------------------------------------------------------------
// Swizzled-tile convention (T2, both-sides, rule #21):
//   LDS tile = [rows][64] bf16, 128B rows.  Physical 16B slot s of row r
//   holds LOGICAL k-group (s ^ (r&7)).  Staging: linear LDS dest, per-lane
//   pre-swizzled global source: lane L covers row base+(L>>3), slot L&7,
//   so its global col-group is (L&7)^(L>>3)  (k-invariant).
//   Reads: logical group G of row r lives at slot G ^ (r&7); fragment rows
//   (..*16 + n16) have r&7 == n16&7.  Quarter-wave bank check: 16 lanes
//   (q4 fixed) hit 8 distinct 16B slots = 32 banks, 2 accesses/bank = min.
// ---------------------------------------------------------------------------

// ---------------------------------------------------------------------------
// Fused QKV projection + RoPE, 128x64 tiles (768 blocks = 3/CU), BK=64,
// 2-phase pipeline, swizzled 128B-row LDS tiles (conflict-free frag reads).
// (byte-identical to the R5 version that passed)
// ---------------------------------------------------------------------------
__global__ __launch_bounds__(256) void qkv_gemm(const bf16_t* __restrict__ Xb,
                                                const bf16_t* __restrict__ Wqb,
                                                const bf16_t* __restrict__ Wkb,
                                                const bf16_t* __restrict__ Wvb,
                                                bf16_t* __restrict__ Qb,
                                                bf16_t* __restrict__ Kb,
                                                bf16_t* __restrict__ Vt)
{
    __shared__ alignas(16) bf16_t sa0[128 * 64], sa1[128 * 64];   // 16KB each
    __shared__ alignas(16) bf16_t sb0[64 * 64],  sb1[64 * 64];    // 8KB each
    const int t = threadIdx.x;
    const int lane = t & 63;
    const int w  = t >> 6;
    const int n16 = lane & 15;
    const int q4  = lane >> 4;
    f32x4 acc[2][4] = {};

    const int m0 = blockIdx.x * 128;
    const int n0 = blockIdx.y * 64;

    const bf16_t* B;
    int mode, nc;
    if (n0 < NH * HD)              { B = Wqb + (size_t)n0 * HID;                     mode = 0; nc = n0; }
    else if (n0 < NH * HD + KVDIM) { B = Wkb + (size_t)(n0 - NH * HD) * HID;         mode = 1; nc = n0 - NH * HD; }
    else                           { B = Wvb + (size_t)(n0 - NH * HD - KVDIM) * HID; mode = 2; nc = n0 - NH * HD - KVDIM; }

    const int lrow8 = lane >> 3;                 // 0..7 (row within 8-row chunk)
    const int lgrp  = (lane & 7) ^ lrow8;        // pre-swizzled source col-group
    const bf16_t* ag = Xb + (size_t)(m0 + w * 8 + lrow8) * HID + lgrp * 8;
    const bf16_t* bg = B  + (size_t)(w * 8 + lrow8) * HID + lgrp * 8;

    auto stage = [&](bf16_t* da, bf16_t* db, int k0) {
#pragma unroll
        for (int s = 0; s < 4; ++s)     // A: 128 rows = 16 chunks, 4/wave
            load_lds16(ag + (size_t)(s * 32) * HID + k0, da + (w * 8 + s * 32) * 64);
#pragma unroll
        for (int s = 0; s < 2; ++s)     // B: 64 rows = 8 chunks, 2/wave
            load_lds16(bg + (size_t)(s * 32) * HID + k0, db + (w * 8 + s * 32) * 64);
    };
    auto mma_step = [&](const bf16_t* sa, const bf16_t* sb) {
#pragma unroll
        for (int kk = 0; kk < 2; ++kk) {
            const int xo = ((kk * 4 + q4) ^ (n16 & 7)) * 8;
            bf16x8 bfrag[4];
#pragma unroll
            for (int j = 0; j < 4; ++j)
                bfrag[j] = *(const bf16x8*)&sb[(j * 16 + n16) * 64 + xo];
#pragma unroll
            for (int i = 0; i < 2; ++i) {
                bf16x8 af = *(const bf16x8*)&sa[(w * 32 + i * 16 + n16) * 64 + xo];
#pragma unroll
                for (int j = 0; j < 4; ++j)
                    acc[i][j] = __builtin_amdgcn_mfma_f32_16x16x32_bf16(af, bfrag[j], acc[i][j], 0, 0, 0);
            }
        }
    };

    stage(sa0, sb0, 0);
    __syncthreads();
    for (int k0 = 0; k0 < HID; k0 += 128) {
        if (k0 + 64 < HID) stage(sa1, sb1, k0 + 64);
        mma_step(sa0, sb0);
        __syncthreads();
        if (k0 + 128 < HID) stage(sa0, sb0, k0 + 128);
        mma_step(sa1, sb1);
        __syncthreads();
    }

    if (mode < 2) {
        // ---- RoPE in registers: d = jt*16+n16 (jt<2), partner at jt+2 ----
#pragma unroll
        for (int jt = 0; jt < 2; ++jt) {
            float dd = (float)(jt * 16 + n16);
            float inv = exp2f(-dd * ROPE_L);
#pragma unroll
            for (int i = 0; i < 2; ++i) {
#pragma unroll
                for (int r = 0; r < 4; ++r) {
                    int pos = m0 + w * 32 + i * 16 + q4 * 4 + r;
                    float ang = (float)pos * inv;
                    float sn, cs;
                    sincosf(ang, &sn, &cs);
                    float x1 = acc[i][jt][r], x2 = acc[i][jt + 2][r];
                    acc[i][jt][r]     = x1 * cs - x2 * sn;
                    acc[i][jt + 2][r] = x2 * cs + x1 * sn;
                }
            }
        }
        const float osc = (mode == 0) ? QSCALE : 1.0f;
        bf16_t* dst = (mode == 0) ? Qb : Kb;
        const int ld = (mode == 0) ? NH * HD : KVDIM;
#pragma unroll
        for (int i = 0; i < 2; ++i)
#pragma unroll
            for (int j = 0; j < 4; ++j) {
                int row = m0 + w * 32 + i * 16 + q4 * 4;
                int col = nc + j * 16 + n16;
#pragma unroll
                for (int r = 0; r < 4; ++r)
                    dst[(size_t)(row + r) * ld + col] = (bf16_t)(acc[i][j][r] * osc);
            }
    } else {
        // ---- V: store transposed ----
#pragma unroll
        for (int i = 0; i < 2; ++i)
#pragma unroll
            for (int j = 0; j < 4; ++j) {
                int row = m0 + w * 32 + i * 16 + q4 * 4;
                int col = nc + j * 16 + n16;
#pragma unroll
                for (int r = 0; r < 4; ++r)
                    Vt[(size_t)col * SEQ + row + r] = (bf16_t)acc[i][j][r];
            }
    }
}

// ---------------------------------------------------------------------------
// O projection, 128x64 tiles (512 blocks), BK=64, 2-phase, swizzled tiles.
// (byte-identical to the R5 version that passed)
// ---------------------------------------------------------------------------
__global__ __launch_bounds__(256) void o_gemm(const bf16_t* __restrict__ A,
                                              const bf16_t* __restrict__ Bw,
                                              float* __restrict__ C)
{
    __shared__ alignas(16) bf16_t sa0[128 * 64], sa1[128 * 64];
    __shared__ alignas(16) bf16_t sb0[64 * 64],  sb1[64 * 64];
    const int t = threadIdx.x;
    const int lane = t & 63;
    const int w  = t >> 6;
    const int n16 = lane & 15;
    const int q4  = lane >> 4;
    f32x4 acc[2][4] = {};

    const int m0 = blockIdx.x * 128;
    const int n0 = blockIdx.y * 64;

    const int lrow8 = lane >> 3;
    const int lgrp  = (lane & 7) ^ lrow8;
    const bf16_t* ag = A  + (size_t)(m0 + w * 8 + lrow8) * HID + lgrp * 8;
    const bf16_t* bg = Bw + (size_t)(n0 + w * 8 + lrow8) * HID + lgrp * 8;

    auto stage = [&](bf16_t* da, bf16_t* db, int k0) {
#pragma unroll
        for (int s = 0; s < 4; ++s)
            load_lds16(ag + (size_t)(s * 32) * HID + k0, da + (w * 8 + s * 32) * 64);
#pragma unroll
        for (int s = 0; s < 2; ++s)
            load_lds16(bg + (size_t)(s * 32) * HID + k0, db + (w * 8 + s * 32) * 64);
    };
    auto mma_step = [&](const bf16_t* sa, const bf16_t* sb) {
#pragma unroll
        for (int kk = 0; kk < 2; ++kk) {
            const int xo = ((kk * 4 + q4) ^ (n16 & 7)) * 8;
            bf16x8 bfrag[4];
#pragma unroll
            for (int j = 0; j < 4; ++j)
                bfrag[j] = *(const bf16x8*)&sb[(j * 16 + n16) * 64 + xo];
#pragma unroll
            for (int i = 0; i < 2; ++i) {
                bf16x8 af = *(const bf16x8*)&sa[(w * 32 + i * 16 + n16) * 64 + xo];
#pragma unroll
                for (int j = 0; j < 4; ++j)
                    acc[i][j] = __builtin_amdgcn_mfma_f32_16x16x32_bf16(af, bfrag[j], acc[i][j], 0, 0, 0);
            }
        }
    };

    stage(sa0, sb0, 0);
    __syncthreads();
    for (int k0 = 0; k0 < HID; k0 += 128) {
        if (k0 + 64 < HID) stage(sa1, sb1, k0 + 64);
        mma_step(sa0, sb0);
        __syncthreads();
        if (k0 + 128 < HID) stage(sa0, sb0, k0 + 128);
        mma_step(sa1, sb1);
        __syncthreads();
    }

#pragma unroll
    for (int i = 0; i < 2; ++i)
#pragma unroll
        for (int j = 0; j < 4; ++j) {
            int row = m0 + w * 32 + i * 16 + q4 * 4;
            int col = n0 + j * 16 + n16;
#pragma unroll
            for (int r = 0; r < 4; ++r)
                C[(size_t)(row + r) * HID + col] = acc[i][j][r];
        }
}

// ---------------------------------------------------------------------------
// MFMA causal flash attention: Bq=128, 4 waves x 32 q-rows, 2-phase 64-kv
// pipeline.  NEW this round: K/V staged into swizzled [64][64] 128B-row LDS
// tiles (same convention as the GEMMs) -> the 8-way bank conflict on every
// K/V ds_read_b128 (the measured 3.24M conflict cycles) becomes 2-way-free.
// Restructured source vs the R3 variant (hoisted offsets, flat stage body).
// ---------------------------------------------------------------------------
__global__ __launch_bounds__(256, 3) void attn_mfma(const bf16_t* __restrict__ Qm,
                                                    const bf16_t* __restrict__ Km,
                                                    const bf16_t* __restrict__ Vt,
                                                    bf16_t* __restrict__ Om)
{
    const int bid = blockIdx.x;
    const int h   = bid & (NH - 1);
    const int qt  = (bid < (SEQ / 128) * NH / 2)
                      ? (SEQ / 128 - 1 - (bid >> 5))
                      : ((bid - (SEQ / 128) * NH / 2) >> 5);
    const int q0  = qt * 128;
    const int kvh = h >> 2;            // H/KVH = 4
    const int t    = threadIdx.x;
    const int w    = t >> 6;
    const int lane = t & 63;
    const int n16  = lane & 15;
    const int q4   = lane >> 4;

    __shared__ alignas(16) bf16_t kb0[64 * 64], kb1[64 * 64];   // K: [kv][d] swz, 8KB each
    __shared__ alignas(16) bf16_t vb0[64 * 64], vb1[64 * 64];   // V: [d][kv] swz
    __shared__ alignas(16) bf16_t ps[4][2][32 * 40];            // [wave][k-half] P staging

    // Q fragments in registers: rows q0 + w*32 + i*16 + n16
    bf16x8 qf[2][2];
#pragma unroll
    for (int i = 0; i < 2; ++i) {
        const bf16_t* qp = Qm + (size_t)(q0 + w * 32 + i * 16 + n16) * HID + h * HD;
        qf[i][0] = *(const bf16x8*)(qp + q4 * 8);
        qf[i][1] = *(const bf16x8*)(qp + 32 + q4 * 8);
    }

    f32x4 acc[2][4] = {};
    f32x4 acc_l[2] = {};                 // row-sums of P via ones-MFMA
    const bf16_t one = (bf16_t)1.0f;
    const bf16x8 ones8 = {one, one, one, one, one, one, one, one};

    // staging source addresses (pre-swizzled global col-group, T2 rule #21)
    const int lrow8 = lane >> 3;                 // 0..7
    const int lgrp  = (lane & 7) ^ lrow8;        // source 16B group
    const bf16_t* kgs = Km + (size_t)kvh * HD + (size_t)lrow8 * KVDIM + lgrp * 8;
    const bf16_t* vgs = Vt + (size_t)(kvh * HD + lrow8) * SEQ + lgrp * 8;

    // swizzled fragment-read offsets (hoisted): logical group g at slot g^(r&7)
    const int rx  = n16 & 7;
    const int xo0 = (q4 ^ rx) * 8;               // groups 0..3
    const int xo1 = ((q4 + 4) ^ rx) * 8;         // groups 4..7

    const int ghmax  = 2 * qt + 1;               // last 64-kv tile staged (odd)
    const int my_last = 2 * qt + (w >> 1);       // last 64-kv tile this wave computes
    const int wkey   = (q4 & 2) << 3;            // P-store swizzle
    const int rdkey  = ((n16 >> 2) & 2) << 3;

    auto stage = [&](int gh, bf16_t* kb, bf16_t* vb) {
        const int k0 = gh * 64;
        load_lds16(kgs + (size_t)(k0 + w * 8)      * KVDIM, kb + (w * 8)      * 64);
        load_lds16(kgs + (size_t)(k0 + w * 8 + 32) * KVDIM, kb + (w * 8 + 32) * 64);
        load_lds16(vgs + (size_t)(w * 8)      * SEQ + k0,   vb + (w * 8)      * 64);
        load_lds16(vgs + (size_t)(w * 8 + 32) * SEQ + k0,   vb + (w * 8 + 32) * 64);
    };

    auto compute = [&](int gh, const bf16_t* kbuf, const bf16_t* vbuf) {
        // ---- S' = Q' K^T (log2-domain scores); K frags reused over i ----
        f32x4 st[2][4];
        __builtin_amdgcn_s_setprio(1);
#pragma unroll
        for (int jt = 0; jt < 4; ++jt) {
            bf16x8 kf0 = *(const bf16x8*)&kbuf[(jt * 16 + n16) * 64 + xo0];
            bf16x8 kf1 = *(const bf16x8*)&kbuf[(jt * 16 + n16) * 64 + xo1];
#pragma unroll
            for (int i = 0; i < 2; ++i) {
                f32x4 s = {};
                s = __builtin_amdgcn_mfma_f32_16x16x32_bf16(qf[i][0], kf0, s, 0, 0, 0);
                s = __builtin_amdgcn_mfma_f32_16x16x32_bf16(qf[i][1], kf1, s, 0, 0, 0);
                st[i][jt] = s;
            }
        }
        __builtin_amdgcn_s_setprio(0);

        // ---- causal mask: only this wave's diagonal tile ----
        if (gh == my_last) {
#pragma unroll
            for (int i = 0; i < 2; ++i) {
                int rowb = q0 + w * 32 + i * 16 + q4 * 4;
#pragma unroll
                for (int jt = 0; jt < 4; ++jt) {
                    int colg = gh * 64 + jt * 16 + n16;
#pragma unroll
                    for (int r = 0; r < 4; ++r)
                        if (colg > rowb + r) st[i][jt][r] = -1e30f;
                }
            }
        }

        // ---- exp (raw v_exp_f32 path) ----
#pragma unroll
        for (int i = 0; i < 2; ++i)
#pragma unroll
            for (int jt = 0; jt < 4; ++jt)
#pragma unroll
                for (int r = 0; r < 4; ++r)
                    st[i][jt][r] = EXPFN(st[i][jt][r]);

        // ---- P: C-layout regs -> per-wave LDS, bank-swizzled ----
#pragma unroll
        for (int i = 0; i < 2; ++i)
#pragma unroll
            for (int jt = 0; jt < 4; ++jt) {
                bf16_t* ph = ps[w][jt >> 1];
                int rowb = i * 16 + q4 * 4;
                int csw  = ((jt & 1) * 16 + n16) ^ wkey;
#pragma unroll
                for (int r = 0; r < 4; ++r)
                    ph[(rowb + r) * 40 + csw] = (bf16_t)st[i][jt][r];
            }

        bf16x8 pf[2][2];
#pragma unroll
        for (int i = 0; i < 2; ++i) {
            int ra = (i * 16 + n16) * 40 + ((q4 * 8) ^ rdkey);
            pf[i][0] = *(const bf16x8*)&ps[w][0][ra];
            pf[i][1] = *(const bf16x8*)&ps[w][1][ra];
        }

        __builtin_amdgcn_s_setprio(1);
        // ---- l += row-sum(P) via ones-MFMA ----
#pragma unroll
        for (int i = 0; i < 2; ++i) {
            acc_l[i] = __builtin_amdgcn_mfma_f32_16x16x32_bf16(pf[i][0], ones8, acc_l[i], 0, 0, 0);
            acc_l[i] = __builtin_amdgcn_mfma_f32_16x16x32_bf16(pf[i][1], ones8, acc_l[i], 0, 0, 0);
        }
        // ---- O += P V (V frags reused over i) ----
#pragma unroll
        for (int jd = 0; jd < 4; ++jd) {
            bf16x8 vf0 = *(const bf16x8*)&vbuf[(jd * 16 + n16) * 64 + xo0];
            bf16x8 vf1 = *(const bf16x8*)&vbuf[(jd * 16 + n16) * 64 + xo1];
#pragma unroll
            for (int i = 0; i < 2; ++i) {
                acc[i][jd] = __builtin_amdgcn_mfma_f32_16x16x32_bf16(pf[i][0], vf0, acc[i][jd], 0, 0, 0);
                acc[i][jd] = __builtin_amdgcn_mfma_f32_16x16x32_bf16(pf[i][1], vf1, acc[i][jd], 0, 0, 0);
            }
        }
        __builtin_amdgcn_s_setprio(0);
    };

    // ---- 2-phase pipelined main loop (gh-count = 2qt+2, always even) ----
    stage(0, kb0, vb0);
    __syncthreads();
    for (int gh = 0; gh <= ghmax; gh += 2) {
        if (gh < ghmax) stage(gh + 1, kb1, vb1);
        if (gh <= my_last) compute(gh, kb0, vb0);
        __syncthreads();
        if (gh + 1 < ghmax) stage(gh + 2, kb0, vb0);
        if (gh + 1 <= my_last) compute(gh + 1, kb1, vb1);
        __syncthreads();
    }

    // ---- normalize + store ----
#pragma unroll
    for (int i = 0; i < 2; ++i) {
        float linv[4];
#pragma unroll
        for (int r = 0; r < 4; ++r) linv[r] = 1.0f / acc_l[i][r];
#pragma unroll
        for (int jd = 0; jd < 4; ++jd)
#pragma unroll
            for (int r = 0; r < 4; ++r) {
                int rowg = q0 + w * 32 + i * 16 + q4 * 4 + r;
                Om[(size_t)rowg * HID + h * HD + jd * 16 + n16] = (bf16_t)(acc[i][jd][r] * linv[r]);
            }
    }
}

// ---------------------------------------------------------------------------
extern "C" void kernel_launch(void* const* d_in, const int* in_sizes, int n_in,
                              void* d_out, int out_size, void* d_ws, size_t ws_size,
                              hipStream_t stream)
{
    const float* X  = (const float*)d_in[0];
    const float* Wq = (const float*)d_in[1];
    const float* Wk = (const float*)d_in[2];
    const float* Wv = (const float*)d_in[3];
    const float* Wo = (const float*)d_in[4];
    float* out = (float*)d_out;

    bf16_t* Xb  = (bf16_t*)d_ws;                      // [SEQ][HID]     8 MB
    bf16_t* Wqb = Xb  + (size_t)NX;                   // [2048][2048]   8 MB
    bf16_t* Wkb = Wqb + (size_t)NWQ;                  // [512][2048]    2 MB
    bf16_t* Wvb = Wkb + (size_t)NWK;                  // [512][2048]    2 MB
    bf16_t* Wob = Wvb + (size_t)NWV;                  // [2048][2048]   8 MB
    bf16_t* Qb  = Wob + (size_t)NWO;                  // [SEQ][NH*HD]   8 MB (pre-scaled QSCALE)
    bf16_t* Kb  = Qb  + (size_t)SEQ * (NH * HD);      // [SEQ][KVDIM]   2 MB
    bf16_t* Vt  = Kb  + (size_t)SEQ * KVDIM;          // [KVDIM][SEQ]   2 MB
    bf16_t* Ob  = Vt  + (size_t)SEQ * KVDIM;          // [SEQ][NH*HD]   8 MB

    dim3 blk(256);

    cvt_all<<<dim3((NTOT / 8 + 255) / 256), blk, 0, stream>>>(X, Wq, Wk, Wv, Wo, Xb, Wqb, Wkb, Wvb, Wob);

    qkv_gemm<<<dim3(SEQ / 128, (NH * HD + 2 * KVDIM) / 64), blk, 0, stream>>>(Xb, Wqb, Wkb, Wvb, Qb, Kb, Vt);

    attn_mfma<<<dim3((SEQ / 128) * NH), blk, 0, stream>>>(Qb, Kb, Vt, Ob);

    o_gemm<<<dim3(SEQ / 128, HID / 64), blk, 0, stream>>>(Ob, Wob, out);
}

// Round 7
// 194.184 us; speedup vs baseline: 1.0119x; 1.0119x over previous
//
#include <hip/hip_runtime.h>
#include <hip/hip_bf16.h>
#include <cstdint>
#include <cstddef>

// Problem constants
#define SEQ   2048
#define HID   2048
#define NH    32
#define NKVH  8
#define HD    64
#define KVDIM (NKVH * HD)   // 512

typedef __bf16 bf16_t;
typedef __bf16 bf16x8 __attribute__((ext_vector_type(8)));
typedef float  f32x4  __attribute__((ext_vector_type(4)));
typedef unsigned int u32x2 __attribute__((ext_vector_type(2)));

// log2(10000)/32  (RoPE: theta^(-d/32) = exp2(-d*L))
#define ROPE_L 0.4152410118609203f

#if __has_builtin(__builtin_amdgcn_exp2f)
#define QSCALE 0.18033688011112043f
#define EXPFN(x) __builtin_amdgcn_exp2f(x)
#else
#define QSCALE 0.125f
#define EXPFN(x) __expf(x)
#endif

__device__ __forceinline__ bf16x8 load8(const float* p) {
    const float4 lo = *(const float4*)p;
    const float4 hi = *(const float4*)(p + 4);
    bf16x8 r;
    r[0] = (bf16_t)lo.x; r[1] = (bf16_t)lo.y; r[2] = (bf16_t)lo.z; r[3] = (bf16_t)lo.w;
    r[4] = (bf16_t)hi.x; r[5] = (bf16_t)hi.y; r[6] = (bf16_t)hi.z; r[7] = (bf16_t)hi.w;
    return r;
}

// async global->LDS, 16B per lane; LDS dest = wave-uniform base + lane*16
__device__ __forceinline__ void load_lds16(const bf16_t* g, bf16_t* l) {
    __builtin_amdgcn_global_load_lds((const __attribute__((address_space(1))) void*)g,
                                     (__attribute__((address_space(3))) void*)l,
                                     16, 0, 0);
}

// pack two f32 -> one dword of 2 bf16 (no builtin on gfx950; T12 recipe, m240)
__device__ __forceinline__ unsigned int cvt_pk_bf16(float lo, float hi) {
    unsigned int r;
    asm("v_cvt_pk_bf16_f32 %0, %1, %2" : "=v"(r) : "v"(lo), "v"(hi));
    return r;
}

// ---------------------------------------------------------------------------
// One-shot fp32 -> bf16 conversion of all GEMM operands.
// ---------------------------------------------------------------------------
#define NX  (SEQ * HID)          // 4M
#define NWQ (NH * HD * HID)      // 4M
#define NWK (KVDIM * HID)        // 1M
#define NWV (KVDIM * HID)        // 1M
#define NWO (HID * NH * HD)      // 4M
#define NTOT (NX + NWQ + NWK + NWV + NWO)   // 14M

__global__ __launch_bounds__(256) void cvt_all(const float* __restrict__ X,
                                               const float* __restrict__ Wq,
                                               const float* __restrict__ Wk,
                                               const float* __restrict__ Wv,
                                               const float* __restrict__ Wo,
                                               bf16_t* __restrict__ Xb,
                                               bf16_t* __restrict__ Wqb,
                                               bf16_t* __restrict__ Wkb,
                                               bf16_t* __restrict__ Wvb,
                                               bf16_t* __restrict__ Wob)
{
    size_t i = ((size_t)blockIdx.x * 256 + threadIdx.x) * 8;
    if (i >= NTOT) return;
    const size_t E0 = NX, E1 = E0 + NWQ, E2 = E1 + NWK, E3 = E2 + NWV;
    const float* s; bf16_t* d; size_t off;
    if (i < E0)      { s = X;  d = Xb;  off = i; }
    else if (i < E1) { s = Wq; d = Wqb; off = i - E0; }
    else if (i < E2) { s = Wk; d = Wkb; off = i - E1; }
    else if (i < E3) { s = Wv; d = Wvb; off = i - E2; }
    else             { s = Wo; d = Wob; off = i - E3; }
    *(bf16x8*)(d + off) = load8(s + off);
}

// ---------------------------------------------------------------------------
// Swizzled-tile convention (T2, both-sides, rule #21):
//   LDS tile = [rows][64] bf16, 128B rows.  Physical 16B slot s of row r
//   holds LOGICAL k-group (s ^ (r&7)).  Staging: linear LDS dest, per-lane
//   pre-swizzled global source: lane L covers row base+(L>>3), slot L&7,
//   so its global col-group is (L&7)^(L>>3)  (k-invariant).
//   Reads: logical group G of row r lives at slot G ^ (r&7); fragment rows
//   (..*16 + n16) have r&7 == n16&7.
// ---------------------------------------------------------------------------

// ---------------------------------------------------------------------------
// Fused QKV projection + RoPE.  NEW: 128x128 block tiles, 2x2 waves of
// 64x64 each -> per kk: 8 ds_read_b128 feed 16 MFMAs (2.0 MFMA/read, vs
// 1.33 at 128x64) — the GEMMs were LDS-read-pipe-bound by arithmetic
// (48 reads x 12cy = 576cy vs 320cy MFMA per 64-K step).
// BK=64 double-buffered (64KB LDS, 2 blocks/CU), grid 16x24 = 384.
// ---------------------------------------------------------------------------
__global__ __launch_bounds__(256, 2) void qkv_gemm(const bf16_t* __restrict__ Xb,
                                                   const bf16_t* __restrict__ Wqb,
                                                   const bf16_t* __restrict__ Wkb,
                                                   const bf16_t* __restrict__ Wvb,
                                                   bf16_t* __restrict__ Qb,
                                                   bf16_t* __restrict__ Kb,
                                                   bf16_t* __restrict__ Vt)
{
    __shared__ alignas(16) bf16_t sa0[128 * 64], sa1[128 * 64];   // 16KB each
    __shared__ alignas(16) bf16_t sb0[128 * 64], sb1[128 * 64];   // 16KB each
    const int t = threadIdx.x;
    const int lane = t & 63;
    const int w  = t >> 6;
    const int n16 = lane & 15;
    const int q4  = lane >> 4;
    const int wm = (w >> 1) * 64;        // wave tile origin in M
    const int wn = (w & 1) * 64;         // wave tile origin in N (head-aligned)
    f32x4 acc[4][4] = {};

    const int m0 = blockIdx.x * 128;
    const int n0 = blockIdx.y * 128;

    const bf16_t* B;
    int mode, nc;
    if (n0 < NH * HD)              { B = Wqb + (size_t)n0 * HID;                     mode = 0; nc = n0; }
    else if (n0 < NH * HD + KVDIM) { B = Wkb + (size_t)(n0 - NH * HD) * HID;         mode = 1; nc = n0 - NH * HD; }
    else                           { B = Wvb + (size_t)(n0 - NH * HD - KVDIM) * HID; mode = 2; nc = n0 - NH * HD - KVDIM; }

    const int lrow8 = lane >> 3;                 // 0..7 (row within 8-row chunk)
    const int lgrp  = (lane & 7) ^ lrow8;        // pre-swizzled source col-group
    const bf16_t* ag = Xb + (size_t)(m0 + w * 8 + lrow8) * HID + lgrp * 8;
    const bf16_t* bg = B  + (size_t)(w * 8 + lrow8) * HID + lgrp * 8;

    auto stage = [&](bf16_t* da, bf16_t* db, int k0) {
#pragma unroll
        for (int s = 0; s < 4; ++s) {   // A,B: 128 rows = 16 chunks of 8, 4/wave each
            load_lds16(ag + (size_t)(s * 32) * HID + k0, da + (w * 8 + s * 32) * 64);
            load_lds16(bg + (size_t)(s * 32) * HID + k0, db + (w * 8 + s * 32) * 64);
        }
    };
    auto mma_step = [&](const bf16_t* sa, const bf16_t* sb) {
#pragma unroll
        for (int kk = 0; kk < 2; ++kk) {
            const int xo = ((kk * 4 + q4) ^ (n16 & 7)) * 8;
            bf16x8 bfrag[4], afrag[4];
#pragma unroll
            for (int j = 0; j < 4; ++j)
                bfrag[j] = *(const bf16x8*)&sb[(wn + j * 16 + n16) * 64 + xo];
#pragma unroll
            for (int i = 0; i < 4; ++i)
                afrag[i] = *(const bf16x8*)&sa[(wm + i * 16 + n16) * 64 + xo];
#pragma unroll
            for (int i = 0; i < 4; ++i)
#pragma unroll
                for (int j = 0; j < 4; ++j)
                    acc[i][j] = __builtin_amdgcn_mfma_f32_16x16x32_bf16(afrag[i], bfrag[j], acc[i][j], 0, 0, 0);
        }
    };

    stage(sa0, sb0, 0);
    __syncthreads();
    for (int k0 = 0; k0 < HID; k0 += 128) {
        if (k0 + 64 < HID) stage(sa1, sb1, k0 + 64);
        mma_step(sa0, sb0);
        __syncthreads();
        if (k0 + 128 < HID) stage(sa0, sb0, k0 + 128);
        mma_step(sa1, sb1);
        __syncthreads();
    }

    if (mode < 2) {
        // ---- RoPE in registers: wave covers one head (wn mult of HD) ----
        // d = jt*16+n16 (jt<2), partner at jt+2 (d+32)
#pragma unroll
        for (int jt = 0; jt < 2; ++jt) {
            float dd = (float)(jt * 16 + n16);
            float inv = exp2f(-dd * ROPE_L);
#pragma unroll
            for (int i = 0; i < 4; ++i) {
#pragma unroll
                for (int r = 0; r < 4; ++r) {
                    int pos = m0 + wm + i * 16 + q4 * 4 + r;
                    float ang = (float)pos * inv;
                    float sn, cs;
                    sincosf(ang, &sn, &cs);
                    float x1 = acc[i][jt][r], x2 = acc[i][jt + 2][r];
                    acc[i][jt][r]     = x1 * cs - x2 * sn;
                    acc[i][jt + 2][r] = x2 * cs + x1 * sn;
                }
            }
        }
        const float osc = (mode == 0) ? QSCALE : 1.0f;
        bf16_t* dst = (mode == 0) ? Qb : Kb;
        const int ld = (mode == 0) ? NH * HD : KVDIM;
#pragma unroll
        for (int i = 0; i < 4; ++i)
#pragma unroll
            for (int j = 0; j < 4; ++j) {
                int row = m0 + wm + i * 16 + q4 * 4;
                int col = nc + wn + j * 16 + n16;
#pragma unroll
                for (int r = 0; r < 4; ++r)
                    dst[(size_t)(row + r) * ld + col] = (bf16_t)(acc[i][j][r] * osc);
            }
    } else {
        // ---- V: store transposed ----
#pragma unroll
        for (int i = 0; i < 4; ++i)
#pragma unroll
            for (int j = 0; j < 4; ++j) {
                int row = m0 + wm + i * 16 + q4 * 4;
                int col = nc + wn + j * 16 + n16;
#pragma unroll
                for (int r = 0; r < 4; ++r)
                    Vt[(size_t)col * SEQ + row + r] = (bf16_t)acc[i][j][r];
            }
    }
}

// ---------------------------------------------------------------------------
// O projection: same 128x128 / 64x64-wave structure, grid 16x16 = 256.
// ---------------------------------------------------------------------------
__global__ __launch_bounds__(256, 2) void o_gemm(const bf16_t* __restrict__ A,
                                                 const bf16_t* __restrict__ Bw,
                                                 float* __restrict__ C)
{
    __shared__ alignas(16) bf16_t sa0[128 * 64], sa1[128 * 64];
    __shared__ alignas(16) bf16_t sb0[128 * 64], sb1[128 * 64];
    const int t = threadIdx.x;
    const int lane = t & 63;
    const int w  = t >> 6;
    const int n16 = lane & 15;
    const int q4  = lane >> 4;
    const int wm = (w >> 1) * 64;
    const int wn = (w & 1) * 64;
    f32x4 acc[4][4] = {};

    const int m0 = blockIdx.x * 128;
    const int n0 = blockIdx.y * 128;

    const int lrow8 = lane >> 3;
    const int lgrp  = (lane & 7) ^ lrow8;
    const bf16_t* ag = A  + (size_t)(m0 + w * 8 + lrow8) * HID + lgrp * 8;
    const bf16_t* bg = Bw + (size_t)(n0 + w * 8 + lrow8) * HID + lgrp * 8;

    auto stage = [&](bf16_t* da, bf16_t* db, int k0) {
#pragma unroll
        for (int s = 0; s < 4; ++s) {
            load_lds16(ag + (size_t)(s * 32) * HID + k0, da + (w * 8 + s * 32) * 64);
            load_lds16(bg + (size_t)(s * 32) * HID + k0, db + (w * 8 + s * 32) * 64);
        }
    };
    auto mma_step = [&](const bf16_t* sa, const bf16_t* sb) {
#pragma unroll
        for (int kk = 0; kk < 2; ++kk) {
            const int xo = ((kk * 4 + q4) ^ (n16 & 7)) * 8;
            bf16x8 bfrag[4], afrag[4];
#pragma unroll
            for (int j = 0; j < 4; ++j)
                bfrag[j] = *(const bf16x8*)&sb[(wn + j * 16 + n16) * 64 + xo];
#pragma unroll
            for (int i = 0; i < 4; ++i)
                afrag[i] = *(const bf16x8*)&sa[(wm + i * 16 + n16) * 64 + xo];
#pragma unroll
            for (int i = 0; i < 4; ++i)
#pragma unroll
                for (int j = 0; j < 4; ++j)
                    acc[i][j] = __builtin_amdgcn_mfma_f32_16x16x32_bf16(afrag[i], bfrag[j], acc[i][j], 0, 0, 0);
        }
    };

    stage(sa0, sb0, 0);
    __syncthreads();
    for (int k0 = 0; k0 < HID; k0 += 128) {
        if (k0 + 64 < HID) stage(sa1, sb1, k0 + 64);
        mma_step(sa0, sb0);
        __syncthreads();
        if (k0 + 128 < HID) stage(sa0, sb0, k0 + 128);
        mma_step(sa1, sb1);
        __syncthreads();
    }

#pragma unroll
    for (int i = 0; i < 4; ++i)
#pragma unroll
        for (int j = 0; j < 4; ++j) {
            int row = m0 + wm + i * 16 + q4 * 4;
            int col = n0 + wn + j * 16 + n16;
#pragma unroll
            for (int r = 0; r < 4; ++r)
                C[(size_t)(row + r) * HID + col] = acc[i][j][r];
        }
}

// ---------------------------------------------------------------------------
// MFMA causal flash attention: Bq=128, 4 waves x 32 q-rows, 2-phase 64-kv
// pipeline, swizzled K/V tiles (R6).  NEW: SWAPPED QK^T — compute
// mfma(K, Q) so each lane holds 4 consecutive kv of ONE q-row.  P values
// then pack in-lane via v_cvt_pk_bf16_f32 and store as 8 ds_write_b64
// (was 32 ds_write_b16 + 32 scalar cvts — the dominant LDS-pipe term,
// ~185cy/wave-tile).  Operand swap costs nothing: kf is already A-layout,
// qf already B-layout.  Mask/l-sum/PV/epilogue layouts unchanged.
// ---------------------------------------------------------------------------
#define PLD 72   // P staging row stride (144B: 16B-aligned rows, conflict-min reads)

__global__ __launch_bounds__(256, 3) void attn_mfma(const bf16_t* __restrict__ Qm,
                                                    const bf16_t* __restrict__ Km,
                                                    const bf16_t* __restrict__ Vt,
                                                    bf16_t* __restrict__ Om)
{
    const int bid = blockIdx.x;
    const int h   = bid & (NH - 1);
    const int qt  = (bid < (SEQ / 128) * NH / 2)
                      ? (SEQ / 128 - 1 - (bid >> 5))
                      : ((bid - (SEQ / 128) * NH / 2) >> 5);
    const int q0  = qt * 128;
    const int kvh = h >> 2;            // H/KVH = 4
    const int t    = threadIdx.x;
    const int w    = t >> 6;
    const int lane = t & 63;
    const int n16  = lane & 15;
    const int q4   = lane >> 4;

    __shared__ alignas(16) bf16_t kb0[64 * 64], kb1[64 * 64];   // K: [kv][d] swz, 8KB each
    __shared__ alignas(16) bf16_t vb0[64 * 64], vb1[64 * 64];   // V: [d][kv] swz
    __shared__ alignas(16) bf16_t ps[4][32 * PLD];              // per-wave P: [q][kv]

    // Q fragments in registers: rows q0 + w*32 + i*16 + n16 (B-layout for swapped QK)
    bf16x8 qf[2][2];
#pragma unroll
    for (int i = 0; i < 2; ++i) {
        const bf16_t* qp = Qm + (size_t)(q0 + w * 32 + i * 16 + n16) * HID + h * HD;
        qf[i][0] = *(const bf16x8*)(qp + q4 * 8);
        qf[i][1] = *(const bf16x8*)(qp + 32 + q4 * 8);
    }

    f32x4 acc[2][4] = {};
    f32x4 acc_l[2] = {};                 // row-sums of P via ones-MFMA
    const bf16_t one = (bf16_t)1.0f;
    const bf16x8 ones8 = {one, one, one, one, one, one, one, one};

    // staging source addresses (pre-swizzled global col-group, T2 rule #21)
    const int lrow8 = lane >> 3;                 // 0..7
    const int lgrp  = (lane & 7) ^ lrow8;        // source 16B group
    const bf16_t* kgs = Km + (size_t)kvh * HD + (size_t)lrow8 * KVDIM + lgrp * 8;
    const bf16_t* vgs = Vt + (size_t)(kvh * HD + lrow8) * SEQ + lgrp * 8;

    // swizzled fragment-read offsets: logical group g at slot g^(r&7)
    const int rx  = n16 & 7;
    const int xo0 = (q4 ^ rx) * 8;               // groups 0..3
    const int xo1 = ((q4 + 4) ^ rx) * 8;         // groups 4..7

    const int ghmax  = 2 * qt + 1;               // last 64-kv tile staged (odd)
    const int my_last = 2 * qt + (w >> 1);       // last 64-kv tile this wave computes

    auto stage = [&](int gh, bf16_t* kb, bf16_t* vb) {
        const int k0 = gh * 64;
        load_lds16(kgs + (size_t)(k0 + w * 8)      * KVDIM, kb + (w * 8)      * 64);
        load_lds16(kgs + (size_t)(k0 + w * 8 + 32) * KVDIM, kb + (w * 8 + 32) * 64);
        load_lds16(vgs + (size_t)(w * 8)      * SEQ + k0,   vb + (w * 8)      * 64);
        load_lds16(vgs + (size_t)(w * 8 + 32) * SEQ + k0,   vb + (w * 8 + 32) * 64);
    };

    auto compute = [&](int gh, const bf16_t* kbuf, const bf16_t* vbuf) {
        // ---- S^T = K Q (swapped): lane holds S[kv = gh*64+jt*16+q4*4+r][q = ..+i*16+n16] ----
        f32x4 st[2][4];
        __builtin_amdgcn_s_setprio(1);
#pragma unroll
        for (int jt = 0; jt < 4; ++jt) {
            bf16x8 kf0 = *(const bf16x8*)&kbuf[(jt * 16 + n16) * 64 + xo0];
            bf16x8 kf1 = *(const bf16x8*)&kbuf[(jt * 16 + n16) * 64 + xo1];
#pragma unroll
            for (int i = 0; i < 2; ++i) {
                f32x4 s = {};
                s = __builtin_amdgcn_mfma_f32_16x16x32_bf16(kf0, qf[i][0], s, 0, 0, 0);
                s = __builtin_amdgcn_mfma_f32_16x16x32_bf16(kf1, qf[i][1], s, 0, 0, 0);
                st[i][jt] = s;
            }
        }
        __builtin_amdgcn_s_setprio(0);

        // ---- causal mask on the diagonal tile (kv > q) ----
        if (gh == my_last) {
#pragma unroll
            for (int i = 0; i < 2; ++i) {
                int qg = q0 + w * 32 + i * 16 + n16;
#pragma unroll
                for (int jt = 0; jt < 4; ++jt) {
                    int kvb = gh * 64 + jt * 16 + q4 * 4;
#pragma unroll
                    for (int r = 0; r < 4; ++r)
                        if (kvb + r > qg) st[i][jt][r] = -1e30f;
                }
            }
        }

        // ---- exp (raw v_exp_f32 path) ----
#pragma unroll
        for (int i = 0; i < 2; ++i)
#pragma unroll
            for (int jt = 0; jt < 4; ++jt)
#pragma unroll
                for (int r = 0; r < 4; ++r)
                    st[i][jt][r] = EXPFN(st[i][jt][r]);

        // ---- P: pack in-lane (kv-consecutive) -> 8 ds_write_b64 ----
#pragma unroll
        for (int i = 0; i < 2; ++i) {
            bf16_t* pr = &ps[w][(i * 16 + n16) * PLD];
#pragma unroll
            for (int jt = 0; jt < 4; ++jt) {
                u32x2 pw;
                pw[0] = cvt_pk_bf16(st[i][jt][0], st[i][jt][1]);
                pw[1] = cvt_pk_bf16(st[i][jt][2], st[i][jt][3]);
                *(u32x2*)&pr[jt * 16 + q4 * 4] = pw;
            }
        }

        bf16x8 pf[2][2];
#pragma unroll
        for (int i = 0; i < 2; ++i) {
            const bf16_t* pr = &ps[w][(i * 16 + n16) * PLD];
            pf[i][0] = *(const bf16x8*)&pr[q4 * 8];
            pf[i][1] = *(const bf16x8*)&pr[32 + q4 * 8];
        }

        __builtin_amdgcn_s_setprio(1);
        // ---- l += row-sum(P) via ones-MFMA ----
#pragma unroll
        for (int i = 0; i < 2; ++i) {
            acc_l[i] = __builtin_amdgcn_mfma_f32_16x16x32_bf16(pf[i][0], ones8, acc_l[i], 0, 0, 0);
            acc_l[i] = __builtin_amdgcn_mfma_f32_16x16x32_bf16(pf[i][1], ones8, acc_l[i], 0, 0, 0);
        }
        // ---- O += P V ----
#pragma unroll
        for (int jd = 0; jd < 4; ++jd) {
            bf16x8 vf0 = *(const bf16x8*)&vbuf[(jd * 16 + n16) * 64 + xo0];
            bf16x8 vf1 = *(const bf16x8*)&vbuf[(jd * 16 + n16) * 64 + xo1];
#pragma unroll
            for (int i = 0; i < 2; ++i) {
                acc[i][jd] = __builtin_amdgcn_mfma_f32_16x16x32_bf16(pf[i][0], vf0, acc[i][jd], 0, 0, 0);
                acc[i][jd] = __builtin_amdgcn_mfma_f32_16x16x32_bf16(pf[i][1], vf1, acc[i][jd], 0, 0, 0);
            }
        }
        __builtin_amdgcn_s_setprio(0);
    };

    // ---- 2-phase pipelined main loop (gh-count = 2qt+2, always even) ----
    stage(0, kb0, vb0);
    __syncthreads();
    for (int gh = 0; gh <= ghmax; gh += 2) {
        if (gh < ghmax) stage(gh + 1, kb1, vb1);
        if (gh <= my_last) compute(gh, kb0, vb0);
        __syncthreads();
        if (gh + 1 < ghmax) stage(gh + 2, kb0, vb0);
        if (gh + 1 <= my_last) compute(gh + 1, kb1, vb1);
        __syncthreads();
    }

    // ---- normalize + store ----
#pragma unroll
    for (int i = 0; i < 2; ++i) {
        float linv[4];
#pragma unroll
        for (int r = 0; r < 4; ++r) linv[r] = 1.0f / acc_l[i][r];
#pragma unroll
        for (int jd = 0; jd < 4; ++jd)
#pragma unroll
            for (int r = 0; r < 4; ++r) {
                int rowg = q0 + w * 32 + i * 16 + q4 * 4 + r;
                Om[(size_t)rowg * HID + h * HD + jd * 16 + n16] = (bf16_t)(acc[i][jd][r] * linv[r]);
            }
    }
}

// ---------------------------------------------------------------------------
extern "C" void kernel_launch(void* const* d_in, const int* in_sizes, int n_in,
                              void* d_out, int out_size, void* d_ws, size_t ws_size,
                              hipStream_t stream)
{
    const float* X  = (const float*)d_in[0];
    const float* Wq = (const float*)d_in[1];
    const float* Wk = (const float*)d_in[2];
    const float* Wv = (const float*)d_in[3];
    const float* Wo = (const float*)d_in[4];
    float* out = (float*)d_out;

    bf16_t* Xb  = (bf16_t*)d_ws;                      // [SEQ][HID]     8 MB
    bf16_t* Wqb = Xb  + (size_t)NX;                   // [2048][2048]   8 MB
    bf16_t* Wkb = Wqb + (size_t)NWQ;                  // [512][2048]    2 MB
    bf16_t* Wvb = Wkb + (size_t)NWK;                  // [512][2048]    2 MB
    bf16_t* Wob = Wvb + (size_t)NWV;                  // [2048][2048]   8 MB
    bf16_t* Qb  = Wob + (size_t)NWO;                  // [SEQ][NH*HD]   8 MB (pre-scaled QSCALE)
    bf16_t* Kb  = Qb  + (size_t)SEQ * (NH * HD);      // [SEQ][KVDIM]   2 MB
    bf16_t* Vt  = Kb  + (size_t)SEQ * KVDIM;          // [KVDIM][SEQ]   2 MB
    bf16_t* Ob  = Vt  + (size_t)SEQ * KVDIM;          // [SEQ][NH*HD]   8 MB

    dim3 blk(256);

    cvt_all<<<dim3((NTOT / 8 + 255) / 256), blk, 0, stream>>>(X, Wq, Wk, Wv, Wo, Xb, Wqb, Wkb, Wvb, Wob);

    // fused QKV projection + RoPE (128x128 tiles, 384 blocks)
    qkv_gemm<<<dim3(SEQ / 128, (NH * HD + 2 * KVDIM) / 128), blk, 0, stream>>>(Xb, Wqb, Wkb, Wvb, Qb, Kb, Vt);

    // causal GQA attention (Bq=128, 512 blocks, swapped-QK + packed P)
    attn_mfma<<<dim3((SEQ / 128) * NH), blk, 0, stream>>>(Qb, Kb, Vt, Ob);

    // output projection (128x128 tiles, 256 blocks)
    o_gemm<<<dim3(SEQ / 128, HID / 128), blk, 0, stream>>>(Ob, Wob, out);
}

// Round 8
// 193.346 us; speedup vs baseline: 1.0163x; 1.0043x over previous
//
#include <hip/hip_runtime.h>
#include <hip/hip_bf16.h>
#include <cstdint>
#include <cstddef>

// Problem constants
#define SEQ   2048
#define HID   2048
#define NH    32
#define NKVH  8
#define HD    64
#define KVDIM (NKVH * HD)   // 512

typedef __bf16 bf16_t;
typedef __bf16 bf16x8 __attribute__((ext_vector_type(8)));
typedef float  f32x4  __attribute__((ext_vector_type(4)));
typedef unsigned int u32x2 __attribute__((ext_vector_type(2)));

// log2(10000)/32  (RoPE: theta^(-d/32) = exp2(-d*L))
#define ROPE_L 0.4152410118609203f

#if __has_builtin(__builtin_amdgcn_exp2f)
#define QSCALE 0.18033688011112043f
#define EXPFN(x) __builtin_amdgcn_exp2f(x)
#else
#define QSCALE 0.125f
#define EXPFN(x) __expf(x)
#endif

// counted-vmcnt barrier primitives (T4, m198/m201 template):
// WAITV8: oldest stage's 8 global_load_lds landed, next stage's 8 stay in flight.
#define WAITV8  do { asm volatile("s_waitcnt vmcnt(8)" ::: "memory"); \
                     __builtin_amdgcn_sched_barrier(0); \
                     __builtin_amdgcn_s_barrier(); } while (0)
#define WAITV0  do { asm volatile("s_waitcnt vmcnt(0)" ::: "memory"); \
                     __builtin_amdgcn_sched_barrier(0); \
                     __builtin_amdgcn_s_barrier(); } while (0)
#define BAR     __builtin_amdgcn_s_barrier()

__device__ __forceinline__ bf16x8 load8(const float* p) {
    const float4 lo = *(const float4*)p;
    const float4 hi = *(const float4*)(p + 4);
    bf16x8 r;
    r[0] = (bf16_t)lo.x; r[1] = (bf16_t)lo.y; r[2] = (bf16_t)lo.z; r[3] = (bf16_t)lo.w;
    r[4] = (bf16_t)hi.x; r[5] = (bf16_t)hi.y; r[6] = (bf16_t)hi.z; r[7] = (bf16_t)hi.w;
    return r;
}

// async global->LDS, 16B per lane; LDS dest = wave-uniform base + lane*16
__device__ __forceinline__ void load_lds16(const bf16_t* g, bf16_t* l) {
    __builtin_amdgcn_global_load_lds((const __attribute__((address_space(1))) void*)g,
                                     (__attribute__((address_space(3))) void*)l,
                                     16, 0, 0);
}

// pack two f32 -> one dword of 2 bf16 (no builtin on gfx950; T12 recipe, m240)
__device__ __forceinline__ unsigned int cvt_pk_bf16(float lo, float hi) {
    unsigned int r;
    asm("v_cvt_pk_bf16_f32 %0, %1, %2" : "=v"(r) : "v"(lo), "v"(hi));
    return r;
}

// ---------------------------------------------------------------------------
// One-shot fp32 -> bf16 conversion of all GEMM operands.
// ---------------------------------------------------------------------------
#define NX  (SEQ * HID)          // 4M
#define NWQ (NH * HD * HID)      // 4M
#define NWK (KVDIM * HID)        // 1M
#define NWV (KVDIM * HID)        // 1M
#define NWO (HID * NH * HD)      // 4M
#define NTOT (NX + NWQ + NWK + NWV + NWO)   // 14M

__global__ __launch_bounds__(256) void cvt_all(const float* __restrict__ X,
                                               const float* __restrict__ Wq,
                                               const float* __restrict__ Wk,
                                               const float* __restrict__ Wv,
                                               const float* __restrict__ Wo,
                                               bf16_t* __restrict__ Xb,
                                               bf16_t* __restrict__ Wqb,
                                               bf16_t* __restrict__ Wkb,
                                               bf16_t* __restrict__ Wvb,
                                               bf16_t* __restrict__ Wob)
{
    size_t i = ((size_t)blockIdx.x * 256 + threadIdx.x) * 8;
    if (i >= NTOT) return;
    const size_t E0 = NX, E1 = E0 + NWQ, E2 = E1 + NWK, E3 = E2 + NWV;
    const float* s; bf16_t* d; size_t off;
    if (i < E0)      { s = X;  d = Xb;  off = i; }
    else if (i < E1) { s = Wq; d = Wqb; off = i - E0; }
    else if (i < E2) { s = Wk; d = Wkb; off = i - E1; }
    else if (i < E3) { s = Wv; d = Wvb; off = i - E2; }
    else             { s = Wo; d = Wob; off = i - E3; }
    *(bf16x8*)(d + off) = load8(s + off);
}

// ---------------------------------------------------------------------------
// Swizzled-tile convention (T2, both-sides, rule #21):
//   LDS tile = [rows][64] bf16, 128B rows.  Physical 16B slot s of row r
//   holds LOGICAL k-group (s ^ (r&7)).  Staging: linear LDS dest, per-lane
//   pre-swizzled global source.  Reads: slot G ^ (r&7).
// ---------------------------------------------------------------------------

// ---------------------------------------------------------------------------
// Fused QKV projection + RoPE, 128x128 tiles, 2x2 waves of 64x64.
// NEW (T4): counted-vmcnt pipeline — raw s_barrier + s_waitcnt vmcnt(8).
// Each stage = 8 global_load_lds; the NEXT stage's 8 stay in flight across
// the barrier, so every stage gets ~2 full compute phases to land (the
// __syncthreads vmcnt(0) drain was the measured 42us plateau: 3 structural
// variants all identical, all pipes <22% busy).
// ---------------------------------------------------------------------------
__global__ __launch_bounds__(256, 2) void qkv_gemm(const bf16_t* __restrict__ Xb,
                                                   const bf16_t* __restrict__ Wqb,
                                                   const bf16_t* __restrict__ Wkb,
                                                   const bf16_t* __restrict__ Wvb,
                                                   bf16_t* __restrict__ Qb,
                                                   bf16_t* __restrict__ Kb,
                                                   bf16_t* __restrict__ Vt)
{
    __shared__ alignas(16) bf16_t sa0[128 * 64], sa1[128 * 64];   // 16KB each
    __shared__ alignas(16) bf16_t sb0[128 * 64], sb1[128 * 64];   // 16KB each
    const int t = threadIdx.x;
    const int lane = t & 63;
    const int w  = t >> 6;
    const int n16 = lane & 15;
    const int q4  = lane >> 4;
    const int wm = (w >> 1) * 64;        // wave tile origin in M
    const int wn = (w & 1) * 64;         // wave tile origin in N (head-aligned)
    f32x4 acc[4][4] = {};

    const int m0 = blockIdx.x * 128;
    const int n0 = blockIdx.y * 128;

    const bf16_t* B;
    int mode, nc;
    if (n0 < NH * HD)              { B = Wqb + (size_t)n0 * HID;                     mode = 0; nc = n0; }
    else if (n0 < NH * HD + KVDIM) { B = Wkb + (size_t)(n0 - NH * HD) * HID;         mode = 1; nc = n0 - NH * HD; }
    else                           { B = Wvb + (size_t)(n0 - NH * HD - KVDIM) * HID; mode = 2; nc = n0 - NH * HD - KVDIM; }

    const int lrow8 = lane >> 3;                 // 0..7 (row within 8-row chunk)
    const int lgrp  = (lane & 7) ^ lrow8;        // pre-swizzled source col-group
    const bf16_t* ag = Xb + (size_t)(m0 + w * 8 + lrow8) * HID + lgrp * 8;
    const bf16_t* bg = B  + (size_t)(w * 8 + lrow8) * HID + lgrp * 8;

    auto stage = [&](bf16_t* da, bf16_t* db, int k0) {
#pragma unroll
        for (int s = 0; s < 4; ++s) {   // A,B: 128 rows = 16 chunks of 8, 4/wave each
            load_lds16(ag + (size_t)(s * 32) * HID + k0, da + (w * 8 + s * 32) * 64);
            load_lds16(bg + (size_t)(s * 32) * HID + k0, db + (w * 8 + s * 32) * 64);
        }
    };
    auto mma_step = [&](const bf16_t* sa, const bf16_t* sb) {
#pragma unroll
        for (int kk = 0; kk < 2; ++kk) {
            const int xo = ((kk * 4 + q4) ^ (n16 & 7)) * 8;
            bf16x8 bfrag[4], afrag[4];
#pragma unroll
            for (int j = 0; j < 4; ++j)
                bfrag[j] = *(const bf16x8*)&sb[(wn + j * 16 + n16) * 64 + xo];
#pragma unroll
            for (int i = 0; i < 4; ++i)
                afrag[i] = *(const bf16x8*)&sa[(wm + i * 16 + n16) * 64 + xo];
#pragma unroll
            for (int i = 0; i < 4; ++i)
#pragma unroll
                for (int j = 0; j < 4; ++j)
                    acc[i][j] = __builtin_amdgcn_mfma_f32_16x16x32_bf16(afrag[i], bfrag[j], acc[i][j], 0, 0, 0);
        }
    };

    // 32 stages of BK=64.  Prologue: stages 0,1.  Loop t issues stage t+2.
    stage(sa0, sb0, 0);
    stage(sa1, sb1, 64);
#pragma unroll 1
    for (int tt = 0; tt < 30; tt += 2) {
        WAITV8;
        mma_step(sa0, sb0);
        BAR;
        stage(sa0, sb0, (tt + 2) * 64);
        WAITV8;
        mma_step(sa1, sb1);
        BAR;
        stage(sa1, sb1, (tt + 3) * 64);
    }
    WAITV8;
    mma_step(sa0, sb0);      // stage 30
    BAR;
    WAITV0;
    mma_step(sa1, sb1);      // stage 31

    if (mode < 2) {
        // ---- RoPE in registers: wave covers one head (wn mult of HD) ----
#pragma unroll
        for (int jt = 0; jt < 2; ++jt) {
            float dd = (float)(jt * 16 + n16);
            float inv = exp2f(-dd * ROPE_L);
#pragma unroll
            for (int i = 0; i < 4; ++i) {
#pragma unroll
                for (int r = 0; r < 4; ++r) {
                    int pos = m0 + wm + i * 16 + q4 * 4 + r;
                    float ang = (float)pos * inv;
                    float sn, cs;
                    sincosf(ang, &sn, &cs);
                    float x1 = acc[i][jt][r], x2 = acc[i][jt + 2][r];
                    acc[i][jt][r]     = x1 * cs - x2 * sn;
                    acc[i][jt + 2][r] = x2 * cs + x1 * sn;
                }
            }
        }
        const float osc = (mode == 0) ? QSCALE : 1.0f;
        bf16_t* dst = (mode == 0) ? Qb : Kb;
        const int ld = (mode == 0) ? NH * HD : KVDIM;
#pragma unroll
        for (int i = 0; i < 4; ++i)
#pragma unroll
            for (int j = 0; j < 4; ++j) {
                int row = m0 + wm + i * 16 + q4 * 4;
                int col = nc + wn + j * 16 + n16;
#pragma unroll
                for (int r = 0; r < 4; ++r)
                    dst[(size_t)(row + r) * ld + col] = (bf16_t)(acc[i][j][r] * osc);
            }
    } else {
        // ---- V: store transposed ----
#pragma unroll
        for (int i = 0; i < 4; ++i)
#pragma unroll
            for (int j = 0; j < 4; ++j) {
                int row = m0 + wm + i * 16 + q4 * 4;
                int col = nc + wn + j * 16 + n16;
#pragma unroll
                for (int r = 0; r < 4; ++r)
                    Vt[(size_t)col * SEQ + row + r] = (bf16_t)acc[i][j][r];
            }
    }
}

// ---------------------------------------------------------------------------
// O projection: 128x128 / 64x64-wave, counted-vmcnt pipeline, grid 16x16.
// ---------------------------------------------------------------------------
__global__ __launch_bounds__(256, 2) void o_gemm(const bf16_t* __restrict__ A,
                                                 const bf16_t* __restrict__ Bw,
                                                 float* __restrict__ C)
{
    __shared__ alignas(16) bf16_t sa0[128 * 64], sa1[128 * 64];
    __shared__ alignas(16) bf16_t sb0[128 * 64], sb1[128 * 64];
    const int t = threadIdx.x;
    const int lane = t & 63;
    const int w  = t >> 6;
    const int n16 = lane & 15;
    const int q4  = lane >> 4;
    const int wm = (w >> 1) * 64;
    const int wn = (w & 1) * 64;
    f32x4 acc[4][4] = {};

    const int m0 = blockIdx.x * 128;
    const int n0 = blockIdx.y * 128;

    const int lrow8 = lane >> 3;
    const int lgrp  = (lane & 7) ^ lrow8;
    const bf16_t* ag = A  + (size_t)(m0 + w * 8 + lrow8) * HID + lgrp * 8;
    const bf16_t* bg = Bw + (size_t)(n0 + w * 8 + lrow8) * HID + lgrp * 8;

    auto stage = [&](bf16_t* da, bf16_t* db, int k0) {
#pragma unroll
        for (int s = 0; s < 4; ++s) {
            load_lds16(ag + (size_t)(s * 32) * HID + k0, da + (w * 8 + s * 32) * 64);
            load_lds16(bg + (size_t)(s * 32) * HID + k0, db + (w * 8 + s * 32) * 64);
        }
    };
    auto mma_step = [&](const bf16_t* sa, const bf16_t* sb) {
#pragma unroll
        for (int kk = 0; kk < 2; ++kk) {
            const int xo = ((kk * 4 + q4) ^ (n16 & 7)) * 8;
            bf16x8 bfrag[4], afrag[4];
#pragma unroll
            for (int j = 0; j < 4; ++j)
                bfrag[j] = *(const bf16x8*)&sb[(wn + j * 16 + n16) * 64 + xo];
#pragma unroll
            for (int i = 0; i < 4; ++i)
                afrag[i] = *(const bf16x8*)&sa[(wm + i * 16 + n16) * 64 + xo];
#pragma unroll
            for (int i = 0; i < 4; ++i)
#pragma unroll
                for (int j = 0; j < 4; ++j)
                    acc[i][j] = __builtin_amdgcn_mfma_f32_16x16x32_bf16(afrag[i], bfrag[j], acc[i][j], 0, 0, 0);
        }
    };

    stage(sa0, sb0, 0);
    stage(sa1, sb1, 64);
#pragma unroll 1
    for (int tt = 0; tt < 30; tt += 2) {
        WAITV8;
        mma_step(sa0, sb0);
        BAR;
        stage(sa0, sb0, (tt + 2) * 64);
        WAITV8;
        mma_step(sa1, sb1);
        BAR;
        stage(sa1, sb1, (tt + 3) * 64);
    }
    WAITV8;
    mma_step(sa0, sb0);
    BAR;
    WAITV0;
    mma_step(sa1, sb1);

#pragma unroll
    for (int i = 0; i < 4; ++i)
#pragma unroll
        for (int j = 0; j < 4; ++j) {
            int row = m0 + wm + i * 16 + q4 * 4;
            int col = n0 + wn + j * 16 + n16;
#pragma unroll
            for (int r = 0; r < 4; ++r)
                C[(size_t)(row + r) * HID + col] = acc[i][j][r];
        }
}

// ---------------------------------------------------------------------------
// MFMA causal flash attention — unchanged from R7 (swapped-QK + packed P,
// which dropped attn below the top-5 cutoff).
// ---------------------------------------------------------------------------
#define PLD 72   // P staging row stride (144B: 16B-aligned rows, conflict-min reads)

__global__ __launch_bounds__(256, 3) void attn_mfma(const bf16_t* __restrict__ Qm,
                                                    const bf16_t* __restrict__ Km,
                                                    const bf16_t* __restrict__ Vt,
                                                    bf16_t* __restrict__ Om)
{
    const int bid = blockIdx.x;
    const int h   = bid & (NH - 1);
    const int qt  = (bid < (SEQ / 128) * NH / 2)
                      ? (SEQ / 128 - 1 - (bid >> 5))
                      : ((bid - (SEQ / 128) * NH / 2) >> 5);
    const int q0  = qt * 128;
    const int kvh = h >> 2;            // H/KVH = 4
    const int t    = threadIdx.x;
    const int w    = t >> 6;
    const int lane = t & 63;
    const int n16  = lane & 15;
    const int q4   = lane >> 4;

    __shared__ alignas(16) bf16_t kb0[64 * 64], kb1[64 * 64];   // K: [kv][d] swz, 8KB each
    __shared__ alignas(16) bf16_t vb0[64 * 64], vb1[64 * 64];   // V: [d][kv] swz
    __shared__ alignas(16) bf16_t ps[4][32 * PLD];              // per-wave P: [q][kv]

    // Q fragments in registers: rows q0 + w*32 + i*16 + n16 (B-layout for swapped QK)
    bf16x8 qf[2][2];
#pragma unroll
    for (int i = 0; i < 2; ++i) {
        const bf16_t* qp = Qm + (size_t)(q0 + w * 32 + i * 16 + n16) * HID + h * HD;
        qf[i][0] = *(const bf16x8*)(qp + q4 * 8);
        qf[i][1] = *(const bf16x8*)(qp + 32 + q4 * 8);
    }

    f32x4 acc[2][4] = {};
    f32x4 acc_l[2] = {};                 // row-sums of P via ones-MFMA
    const bf16_t one = (bf16_t)1.0f;
    const bf16x8 ones8 = {one, one, one, one, one, one, one, one};

    // staging source addresses (pre-swizzled global col-group, T2 rule #21)
    const int lrow8 = lane >> 3;                 // 0..7
    const int lgrp  = (lane & 7) ^ lrow8;        // source 16B group
    const bf16_t* kgs = Km + (size_t)kvh * HD + (size_t)lrow8 * KVDIM + lgrp * 8;
    const bf16_t* vgs = Vt + (size_t)(kvh * HD + lrow8) * SEQ + lgrp * 8;

    // swizzled fragment-read offsets: logical group g at slot g^(r&7)
    const int rx  = n16 & 7;
    const int xo0 = (q4 ^ rx) * 8;               // groups 0..3
    const int xo1 = ((q4 + 4) ^ rx) * 8;         // groups 4..7

    const int ghmax  = 2 * qt + 1;               // last 64-kv tile staged (odd)
    const int my_last = 2 * qt + (w >> 1);       // last 64-kv tile this wave computes

    auto stage = [&](int gh, bf16_t* kb, bf16_t* vb) {
        const int k0 = gh * 64;
        load_lds16(kgs + (size_t)(k0 + w * 8)      * KVDIM, kb + (w * 8)      * 64);
        load_lds16(kgs + (size_t)(k0 + w * 8 + 32) * KVDIM, kb + (w * 8 + 32) * 64);
        load_lds16(vgs + (size_t)(w * 8)      * SEQ + k0,   vb + (w * 8)      * 64);
        load_lds16(vgs + (size_t)(w * 8 + 32) * SEQ + k0,   vb + (w * 8 + 32) * 64);
    };

    auto compute = [&](int gh, const bf16_t* kbuf, const bf16_t* vbuf) {
        // ---- S^T = K Q (swapped): lane holds S[kv = gh*64+jt*16+q4*4+r][q = ..+i*16+n16] ----
        f32x4 st[2][4];
        __builtin_amdgcn_s_setprio(1);
#pragma unroll
        for (int jt = 0; jt < 4; ++jt) {
            bf16x8 kf0 = *(const bf16x8*)&kbuf[(jt * 16 + n16) * 64 + xo0];
            bf16x8 kf1 = *(const bf16x8*)&kbuf[(jt * 16 + n16) * 64 + xo1];
#pragma unroll
            for (int i = 0; i < 2; ++i) {
                f32x4 s = {};
                s = __builtin_amdgcn_mfma_f32_16x16x32_bf16(kf0, qf[i][0], s, 0, 0, 0);
                s = __builtin_amdgcn_mfma_f32_16x16x32_bf16(kf1, qf[i][1], s, 0, 0, 0);
                st[i][jt] = s;
            }
        }
        __builtin_amdgcn_s_setprio(0);

        // ---- causal mask on the diagonal tile (kv > q) ----
        if (gh == my_last) {
#pragma unroll
            for (int i = 0; i < 2; ++i) {
                int qg = q0 + w * 32 + i * 16 + n16;
#pragma unroll
                for (int jt = 0; jt < 4; ++jt) {
                    int kvb = gh * 64 + jt * 16 + q4 * 4;
#pragma unroll
                    for (int r = 0; r < 4; ++r)
                        if (kvb + r > qg) st[i][jt][r] = -1e30f;
                }
            }
        }

        // ---- exp (raw v_exp_f32 path) ----
#pragma unroll
        for (int i = 0; i < 2; ++i)
#pragma unroll
            for (int jt = 0; jt < 4; ++jt)
#pragma unroll
                for (int r = 0; r < 4; ++r)
                    st[i][jt][r] = EXPFN(st[i][jt][r]);

        // ---- P: pack in-lane (kv-consecutive) -> 8 ds_write_b64 ----
#pragma unroll
        for (int i = 0; i < 2; ++i) {
            bf16_t* pr = &ps[w][(i * 16 + n16) * PLD];
#pragma unroll
            for (int jt = 0; jt < 4; ++jt) {
                u32x2 pw;
                pw[0] = cvt_pk_bf16(st[i][jt][0], st[i][jt][1]);
                pw[1] = cvt_pk_bf16(st[i][jt][2], st[i][jt][3]);
                *(u32x2*)&pr[jt * 16 + q4 * 4] = pw;
            }
        }

        bf16x8 pf[2][2];
#pragma unroll
        for (int i = 0; i < 2; ++i) {
            const bf16_t* pr = &ps[w][(i * 16 + n16) * PLD];
            pf[i][0] = *(const bf16x8*)&pr[q4 * 8];
            pf[i][1] = *(const bf16x8*)&pr[32 + q4 * 8];
        }

        __builtin_amdgcn_s_setprio(1);
        // ---- l += row-sum(P) via ones-MFMA ----
#pragma unroll
        for (int i = 0; i < 2; ++i) {
            acc_l[i] = __builtin_amdgcn_mfma_f32_16x16x32_bf16(pf[i][0], ones8, acc_l[i], 0, 0, 0);
            acc_l[i] = __builtin_amdgcn_mfma_f32_16x16x32_bf16(pf[i][1], ones8, acc_l[i], 0, 0, 0);
        }
        // ---- O += P V ----
#pragma unroll
        for (int jd = 0; jd < 4; ++jd) {
            bf16x8 vf0 = *(const bf16x8*)&vbuf[(jd * 16 + n16) * 64 + xo0];
            bf16x8 vf1 = *(const bf16x8*)&vbuf[(jd * 16 + n16) * 64 + xo1];
#pragma unroll
            for (int i = 0; i < 2; ++i) {
                acc[i][jd] = __builtin_amdgcn_mfma_f32_16x16x32_bf16(pf[i][0], vf0, acc[i][jd], 0, 0, 0);
                acc[i][jd] = __builtin_amdgcn_mfma_f32_16x16x32_bf16(pf[i][1], vf1, acc[i][jd], 0, 0, 0);
            }
        }
        __builtin_amdgcn_s_setprio(0);
    };

    // ---- 2-phase pipelined main loop (gh-count = 2qt+2, always even) ----
    stage(0, kb0, vb0);
    __syncthreads();
    for (int gh = 0; gh <= ghmax; gh += 2) {
        if (gh < ghmax) stage(gh + 1, kb1, vb1);
        if (gh <= my_last) compute(gh, kb0, vb0);
        __syncthreads();
        if (gh + 1 < ghmax) stage(gh + 2, kb0, vb0);
        if (gh + 1 <= my_last) compute(gh + 1, kb1, vb1);
        __syncthreads();
    }

    // ---- normalize + store ----
#pragma unroll
    for (int i = 0; i < 2; ++i) {
        float linv[4];
#pragma unroll
        for (int r = 0; r < 4; ++r) linv[r] = 1.0f / acc_l[i][r];
#pragma unroll
        for (int jd = 0; jd < 4; ++jd)
#pragma unroll
            for (int r = 0; r < 4; ++r) {
                int rowg = q0 + w * 32 + i * 16 + q4 * 4 + r;
                Om[(size_t)rowg * HID + h * HD + jd * 16 + n16] = (bf16_t)(acc[i][jd][r] * linv[r]);
            }
    }
}

// ---------------------------------------------------------------------------
extern "C" void kernel_launch(void* const* d_in, const int* in_sizes, int n_in,
                              void* d_out, int out_size, void* d_ws, size_t ws_size,
                              hipStream_t stream)
{
    const float* X  = (const float*)d_in[0];
    const float* Wq = (const float*)d_in[1];
    const float* Wk = (const float*)d_in[2];
    const float* Wv = (const float*)d_in[3];
    const float* Wo = (const float*)d_in[4];
    float* out = (float*)d_out;

    bf16_t* Xb  = (bf16_t*)d_ws;                      // [SEQ][HID]     8 MB
    bf16_t* Wqb = Xb  + (size_t)NX;                   // [2048][2048]   8 MB
    bf16_t* Wkb = Wqb + (size_t)NWQ;                  // [512][2048]    2 MB
    bf16_t* Wvb = Wkb + (size_t)NWK;                  // [512][2048]    2 MB
    bf16_t* Wob = Wvb + (size_t)NWV;                  // [2048][2048]   8 MB
    bf16_t* Qb  = Wob + (size_t)NWO;                  // [SEQ][NH*HD]   8 MB (pre-scaled QSCALE)
    bf16_t* Kb  = Qb  + (size_t)SEQ * (NH * HD);      // [SEQ][KVDIM]   2 MB
    bf16_t* Vt  = Kb  + (size_t)SEQ * KVDIM;          // [KVDIM][SEQ]   2 MB
    bf16_t* Ob  = Vt  + (size_t)SEQ * KVDIM;          // [SEQ][NH*HD]   8 MB

    dim3 blk(256);

    cvt_all<<<dim3((NTOT / 8 + 255) / 256), blk, 0, stream>>>(X, Wq, Wk, Wv, Wo, Xb, Wqb, Wkb, Wvb, Wob);

    // fused QKV projection + RoPE (128x128 tiles, counted-vmcnt pipeline)
    qkv_gemm<<<dim3(SEQ / 128, (NH * HD + 2 * KVDIM) / 128), blk, 0, stream>>>(Xb, Wqb, Wkb, Wvb, Qb, Kb, Vt);

    // causal GQA attention (Bq=128, 512 blocks, swapped-QK + packed P)
    attn_mfma<<<dim3((SEQ / 128) * NH), blk, 0, stream>>>(Qb, Kb, Vt, Ob);

    // output projection (128x128 tiles, counted-vmcnt pipeline)
    o_gemm<<<dim3(SEQ / 128, HID / 128), blk, 0, stream>>>(Ob, Wob, out);
}

// Round 9
// 186.348 us; speedup vs baseline: 1.0544x; 1.0376x over previous
//
#include <hip/hip_runtime.h>
#include <hip/hip_bf16.h>
#include <cstdint>
#include <cstddef>

// Problem constants
#define SEQ   2048
#define HID   2048
#define NH    32
#define NKVH  8
#define HD    64
#define KVDIM (NKVH * HD)   // 512

typedef __bf16 bf16_t;
typedef __bf16 bf16x8 __attribute__((ext_vector_type(8)));
typedef float  f32x4  __attribute__((ext_vector_type(4)));
typedef unsigned int u32x2 __attribute__((ext_vector_type(2)));

// log2(10000)/32  (RoPE: theta^(-d/32) = exp2(-d*L))
#define ROPE_L 0.4152410118609203f

#if __has_builtin(__builtin_amdgcn_exp2f)
#define QSCALE 0.18033688011112043f
#define EXPFN(x) __builtin_amdgcn_exp2f(x)
#else
#define QSCALE 0.125f
#define EXPFN(x) __expf(x)
#endif

// counted-vmcnt barrier primitives (T4): wave waits for its OLDEST stage's
// loads only; the next stage's loads stay in flight across the barrier.
#define WAITV4  do { asm volatile("s_waitcnt vmcnt(4)" ::: "memory"); \
                     __builtin_amdgcn_sched_barrier(0); \
                     __builtin_amdgcn_s_barrier(); } while (0)
#define WAITV0  do { asm volatile("s_waitcnt vmcnt(0)" ::: "memory"); \
                     __builtin_amdgcn_sched_barrier(0); \
                     __builtin_amdgcn_s_barrier(); } while (0)
#define BAR     __builtin_amdgcn_s_barrier()

__device__ __forceinline__ bf16x8 load8(const float* p) {
    const float4 lo = *(const float4*)p;
    const float4 hi = *(const float4*)(p + 4);
    bf16x8 r;
    r[0] = (bf16_t)lo.x; r[1] = (bf16_t)lo.y; r[2] = (bf16_t)lo.z; r[3] = (bf16_t)lo.w;
    r[4] = (bf16_t)hi.x; r[5] = (bf16_t)hi.y; r[6] = (bf16_t)hi.z; r[7] = (bf16_t)hi.w;
    return r;
}

// async global->LDS, 16B per lane; LDS dest = wave-uniform base + lane*16
__device__ __forceinline__ void load_lds16(const bf16_t* g, bf16_t* l) {
    __builtin_amdgcn_global_load_lds((const __attribute__((address_space(1))) void*)g,
                                     (__attribute__((address_space(3))) void*)l,
                                     16, 0, 0);
}

// pack two f32 -> one dword of 2 bf16 (no builtin on gfx950; T12 recipe, m240)
__device__ __forceinline__ unsigned int cvt_pk_bf16(float lo, float hi) {
    unsigned int r;
    asm("v_cvt_pk_bf16_f32 %0, %1, %2" : "=v"(r) : "v"(lo), "v"(hi));
    return r;
}

// ---------------------------------------------------------------------------
// One-shot fp32 -> bf16 conversion of all GEMM operands.
// ---------------------------------------------------------------------------
#define NX  (SEQ * HID)          // 4M
#define NWQ (NH * HD * HID)      // 4M
#define NWK (KVDIM * HID)        // 1M
#define NWV (KVDIM * HID)        // 1M
#define NWO (HID * NH * HD)      // 4M
#define NTOT (NX + NWQ + NWK + NWV + NWO)   // 14M

__global__ __launch_bounds__(256) void cvt_all(const float* __restrict__ X,
                                               const float* __restrict__ Wq,
                                               const float* __restrict__ Wk,
                                               const float* __restrict__ Wv,
                                               const float* __restrict__ Wo,
                                               bf16_t* __restrict__ Xb,
                                               bf16_t* __restrict__ Wqb,
                                               bf16_t* __restrict__ Wkb,
                                               bf16_t* __restrict__ Wvb,
                                               bf16_t* __restrict__ Wob)
{
    size_t i = ((size_t)blockIdx.x * 256 + threadIdx.x) * 8;
    if (i >= NTOT) return;
    const size_t E0 = NX, E1 = E0 + NWQ, E2 = E1 + NWK, E3 = E2 + NWV;
    const float* s; bf16_t* d; size_t off;
    if (i < E0)      { s = X;  d = Xb;  off = i; }
    else if (i < E1) { s = Wq; d = Wqb; off = i - E0; }
    else if (i < E2) { s = Wk; d = Wkb; off = i - E1; }
    else if (i < E3) { s = Wv; d = Wvb; off = i - E2; }
    else             { s = Wo; d = Wob; off = i - E3; }
    *(bf16x8*)(d + off) = load8(s + off);
}

// ---------------------------------------------------------------------------
// Swizzled-tile convention (T2, both-sides, rule #21):
//   LDS tile = [rows][64] bf16, 128B rows.  Physical 16B slot s of row r
//   holds LOGICAL k-group (s ^ (r&7)).  Staging: linear LDS dest, per-lane
//   pre-swizzled global source.  Reads: slot G ^ (r&7).
// ---------------------------------------------------------------------------

// ---------------------------------------------------------------------------
// Fused QKV projection + RoPE, 128x128 tiles.  NEW (R9): 512-thread blocks
// (8 waves in a 4x2 grid of 32x64 wave-tiles) -> 2 blocks/CU = 4 waves/SIMD,
// double the TLP of every previous variant.  Rationale: 4 structural
// variants (drain0/2-phase/128sq/counted-vmcnt) all pinned at 42us with
// 2 waves/SIMD and all pipes <22% busy — the bound is latency exposure at
// low occupancy, not schedule or conflicts.  Counted-vmcnt kept (4 loads
// per wave per stage -> vmcnt(4)).
// ---------------------------------------------------------------------------
__global__ __launch_bounds__(512, 4) void qkv_gemm(const bf16_t* __restrict__ Xb,
                                                   const bf16_t* __restrict__ Wqb,
                                                   const bf16_t* __restrict__ Wkb,
                                                   const bf16_t* __restrict__ Wvb,
                                                   bf16_t* __restrict__ Qb,
                                                   bf16_t* __restrict__ Kb,
                                                   bf16_t* __restrict__ Vt)
{
    __shared__ alignas(16) bf16_t sa0[128 * 64], sa1[128 * 64];   // 16KB each
    __shared__ alignas(16) bf16_t sb0[128 * 64], sb1[128 * 64];   // 16KB each
    const int t = threadIdx.x;
    const int lane = t & 63;
    const int w  = t >> 6;               // 0..7
    const int n16 = lane & 15;
    const int q4  = lane >> 4;
    const int wm = (w >> 1) * 32;        // wave tile origin in M (0,32,64,96)
    const int wn = (w & 1) * 64;         // wave tile origin in N (head-aligned)
    f32x4 acc[2][4] = {};

    const int m0 = blockIdx.x * 128;
    const int n0 = blockIdx.y * 128;

    const bf16_t* B;
    int mode, nc;
    if (n0 < NH * HD)              { B = Wqb + (size_t)n0 * HID;                     mode = 0; nc = n0; }
    else if (n0 < NH * HD + KVDIM) { B = Wkb + (size_t)(n0 - NH * HD) * HID;         mode = 1; nc = n0 - NH * HD; }
    else                           { B = Wvb + (size_t)(n0 - NH * HD - KVDIM) * HID; mode = 2; nc = n0 - NH * HD - KVDIM; }

    const int lrow8 = lane >> 3;                 // 0..7 (row within 8-row chunk)
    const int lgrp  = (lane & 7) ^ lrow8;        // pre-swizzled source col-group
    const bf16_t* ag = Xb + (size_t)(m0 + w * 16 + lrow8) * HID + lgrp * 8;
    const bf16_t* bg = B  + (size_t)(w * 16 + lrow8) * HID + lgrp * 8;

    auto stage = [&](bf16_t* da, bf16_t* db, int k0) {
        // wave w covers A rows [w*16, w*16+16) and B rows [w*16, w*16+16)
        load_lds16(ag + k0,                      da + (w * 16) * 64);
        load_lds16(ag + (size_t)8 * HID + k0,    da + (w * 16 + 8) * 64);
        load_lds16(bg + k0,                      db + (w * 16) * 64);
        load_lds16(bg + (size_t)8 * HID + k0,    db + (w * 16 + 8) * 64);
    };
    auto mma_step = [&](const bf16_t* sa, const bf16_t* sb) {
#pragma unroll
        for (int kk = 0; kk < 2; ++kk) {
            const int xo = ((kk * 4 + q4) ^ (n16 & 7)) * 8;
            bf16x8 bfrag[4], afrag[2];
#pragma unroll
            for (int j = 0; j < 4; ++j)
                bfrag[j] = *(const bf16x8*)&sb[(wn + j * 16 + n16) * 64 + xo];
#pragma unroll
            for (int i = 0; i < 2; ++i)
                afrag[i] = *(const bf16x8*)&sa[(wm + i * 16 + n16) * 64 + xo];
#pragma unroll
            for (int i = 0; i < 2; ++i)
#pragma unroll
                for (int j = 0; j < 4; ++j)
                    acc[i][j] = __builtin_amdgcn_mfma_f32_16x16x32_bf16(afrag[i], bfrag[j], acc[i][j], 0, 0, 0);
        }
    };

    // 32 stages of BK=64.  Prologue: stages 0,1.  Loop t issues stage t+2.
    stage(sa0, sb0, 0);
    stage(sa1, sb1, 64);
#pragma unroll 1
    for (int tt = 0; tt < 30; tt += 2) {
        WAITV4;
        mma_step(sa0, sb0);
        BAR;
        stage(sa0, sb0, (tt + 2) * 64);
        WAITV4;
        mma_step(sa1, sb1);
        BAR;
        stage(sa1, sb1, (tt + 3) * 64);
    }
    WAITV4;
    mma_step(sa0, sb0);      // stage 30
    BAR;
    WAITV0;
    mma_step(sa1, sb1);      // stage 31

    if (mode < 2) {
        // ---- RoPE in registers: wave covers one head (wn mult of HD) ----
#pragma unroll
        for (int jt = 0; jt < 2; ++jt) {
            float dd = (float)(jt * 16 + n16);
            float inv = exp2f(-dd * ROPE_L);
#pragma unroll
            for (int i = 0; i < 2; ++i) {
#pragma unroll
                for (int r = 0; r < 4; ++r) {
                    int pos = m0 + wm + i * 16 + q4 * 4 + r;
                    float ang = (float)pos * inv;
                    float sn, cs;
                    sincosf(ang, &sn, &cs);
                    float x1 = acc[i][jt][r], x2 = acc[i][jt + 2][r];
                    acc[i][jt][r]     = x1 * cs - x2 * sn;
                    acc[i][jt + 2][r] = x2 * cs + x1 * sn;
                }
            }
        }
        const float osc = (mode == 0) ? QSCALE : 1.0f;
        bf16_t* dst = (mode == 0) ? Qb : Kb;
        const int ld = (mode == 0) ? NH * HD : KVDIM;
#pragma unroll
        for (int i = 0; i < 2; ++i)
#pragma unroll
            for (int j = 0; j < 4; ++j) {
                int row = m0 + wm + i * 16 + q4 * 4;
                int col = nc + wn + j * 16 + n16;
#pragma unroll
                for (int r = 0; r < 4; ++r)
                    dst[(size_t)(row + r) * ld + col] = (bf16_t)(acc[i][j][r] * osc);
            }
    } else {
        // ---- V: store transposed ----
#pragma unroll
        for (int i = 0; i < 2; ++i)
#pragma unroll
            for (int j = 0; j < 4; ++j) {
                int row = m0 + wm + i * 16 + q4 * 4;
                int col = nc + wn + j * 16 + n16;
#pragma unroll
                for (int r = 0; r < 4; ++r)
                    Vt[(size_t)col * SEQ + row + r] = (bf16_t)acc[i][j][r];
            }
    }
}

// ---------------------------------------------------------------------------
// O projection: 512-thread 128x128 blocks, grid 16x16 = 256 = exactly
// 1 block/CU (perfect balance), counted-vmcnt pipeline.
// ---------------------------------------------------------------------------
__global__ __launch_bounds__(512, 4) void o_gemm(const bf16_t* __restrict__ A,
                                                 const bf16_t* __restrict__ Bw,
                                                 float* __restrict__ C)
{
    __shared__ alignas(16) bf16_t sa0[128 * 64], sa1[128 * 64];
    __shared__ alignas(16) bf16_t sb0[128 * 64], sb1[128 * 64];
    const int t = threadIdx.x;
    const int lane = t & 63;
    const int w  = t >> 6;
    const int n16 = lane & 15;
    const int q4  = lane >> 4;
    const int wm = (w >> 1) * 32;
    const int wn = (w & 1) * 64;
    f32x4 acc[2][4] = {};

    const int m0 = blockIdx.x * 128;
    const int n0 = blockIdx.y * 128;

    const int lrow8 = lane >> 3;
    const int lgrp  = (lane & 7) ^ lrow8;
    const bf16_t* ag = A  + (size_t)(m0 + w * 16 + lrow8) * HID + lgrp * 8;
    const bf16_t* bg = Bw + (size_t)(n0 + w * 16 + lrow8) * HID + lgrp * 8;

    auto stage = [&](bf16_t* da, bf16_t* db, int k0) {
        load_lds16(ag + k0,                      da + (w * 16) * 64);
        load_lds16(ag + (size_t)8 * HID + k0,    da + (w * 16 + 8) * 64);
        load_lds16(bg + k0,                      db + (w * 16) * 64);
        load_lds16(bg + (size_t)8 * HID + k0,    db + (w * 16 + 8) * 64);
    };
    auto mma_step = [&](const bf16_t* sa, const bf16_t* sb) {
#pragma unroll
        for (int kk = 0; kk < 2; ++kk) {
            const int xo = ((kk * 4 + q4) ^ (n16 & 7)) * 8;
            bf16x8 bfrag[4], afrag[2];
#pragma unroll
            for (int j = 0; j < 4; ++j)
                bfrag[j] = *(const bf16x8*)&sb[(wn + j * 16 + n16) * 64 + xo];
#pragma unroll
            for (int i = 0; i < 2; ++i)
                afrag[i] = *(const bf16x8*)&sa[(wm + i * 16 + n16) * 64 + xo];
#pragma unroll
            for (int i = 0; i < 2; ++i)
#pragma unroll
                for (int j = 0; j < 4; ++j)
                    acc[i][j] = __builtin_amdgcn_mfma_f32_16x16x32_bf16(afrag[i], bfrag[j], acc[i][j], 0, 0, 0);
        }
    };

    stage(sa0, sb0, 0);
    stage(sa1, sb1, 64);
#pragma unroll 1
    for (int tt = 0; tt < 30; tt += 2) {
        WAITV4;
        mma_step(sa0, sb0);
        BAR;
        stage(sa0, sb0, (tt + 2) * 64);
        WAITV4;
        mma_step(sa1, sb1);
        BAR;
        stage(sa1, sb1, (tt + 3) * 64);
    }
    WAITV4;
    mma_step(sa0, sb0);
    BAR;
    WAITV0;
    mma_step(sa1, sb1);

#pragma unroll
    for (int i = 0; i < 2; ++i)
#pragma unroll
        for (int j = 0; j < 4; ++j) {
            int row = m0 + wm + i * 16 + q4 * 4;
            int col = n0 + wn + j * 16 + n16;
#pragma unroll
            for (int r = 0; r < 4; ++r)
                C[(size_t)(row + r) * HID + col] = acc[i][j][r];
        }
}

// ---------------------------------------------------------------------------
// MFMA causal flash attention — unchanged from R7/R8 (swapped-QK + packed P).
// ---------------------------------------------------------------------------
#define PLD 72   // P staging row stride (144B: 16B-aligned rows, conflict-min reads)

__global__ __launch_bounds__(256, 3) void attn_mfma(const bf16_t* __restrict__ Qm,
                                                    const bf16_t* __restrict__ Km,
                                                    const bf16_t* __restrict__ Vt,
                                                    bf16_t* __restrict__ Om)
{
    const int bid = blockIdx.x;
    const int h   = bid & (NH - 1);
    const int qt  = (bid < (SEQ / 128) * NH / 2)
                      ? (SEQ / 128 - 1 - (bid >> 5))
                      : ((bid - (SEQ / 128) * NH / 2) >> 5);
    const int q0  = qt * 128;
    const int kvh = h >> 2;            // H/KVH = 4
    const int t    = threadIdx.x;
    const int w    = t >> 6;
    const int lane = t & 63;
    const int n16  = lane & 15;
    const int q4   = lane >> 4;

    __shared__ alignas(16) bf16_t kb0[64 * 64], kb1[64 * 64];   // K: [kv][d] swz, 8KB each
    __shared__ alignas(16) bf16_t vb0[64 * 64], vb1[64 * 64];   // V: [d][kv] swz
    __shared__ alignas(16) bf16_t ps[4][32 * PLD];              // per-wave P: [q][kv]

    // Q fragments in registers: rows q0 + w*32 + i*16 + n16 (B-layout for swapped QK)
    bf16x8 qf[2][2];
#pragma unroll
    for (int i = 0; i < 2; ++i) {
        const bf16_t* qp = Qm + (size_t)(q0 + w * 32 + i * 16 + n16) * HID + h * HD;
        qf[i][0] = *(const bf16x8*)(qp + q4 * 8);
        qf[i][1] = *(const bf16x8*)(qp + 32 + q4 * 8);
    }

    f32x4 acc[2][4] = {};
    f32x4 acc_l[2] = {};                 // row-sums of P via ones-MFMA
    const bf16_t one = (bf16_t)1.0f;
    const bf16x8 ones8 = {one, one, one, one, one, one, one, one};

    // staging source addresses (pre-swizzled global col-group, T2 rule #21)
    const int lrow8 = lane >> 3;                 // 0..7
    const int lgrp  = (lane & 7) ^ lrow8;        // source 16B group
    const bf16_t* kgs = Km + (size_t)kvh * HD + (size_t)lrow8 * KVDIM + lgrp * 8;
    const bf16_t* vgs = Vt + (size_t)(kvh * HD + lrow8) * SEQ + lgrp * 8;

    // swizzled fragment-read offsets: logical group g at slot g^(r&7)
    const int rx  = n16 & 7;
    const int xo0 = (q4 ^ rx) * 8;               // groups 0..3
    const int xo1 = ((q4 + 4) ^ rx) * 8;         // groups 4..7

    const int ghmax  = 2 * qt + 1;               // last 64-kv tile staged (odd)
    const int my_last = 2 * qt + (w >> 1);       // last 64-kv tile this wave computes

    auto stage = [&](int gh, bf16_t* kb, bf16_t* vb) {
        const int k0 = gh * 64;
        load_lds16(kgs + (size_t)(k0 + w * 8)      * KVDIM, kb + (w * 8)      * 64);
        load_lds16(kgs + (size_t)(k0 + w * 8 + 32) * KVDIM, kb + (w * 8 + 32) * 64);
        load_lds16(vgs + (size_t)(w * 8)      * SEQ + k0,   vb + (w * 8)      * 64);
        load_lds16(vgs + (size_t)(w * 8 + 32) * SEQ + k0,   vb + (w * 8 + 32) * 64);
    };

    auto compute = [&](int gh, const bf16_t* kbuf, const bf16_t* vbuf) {
        // ---- S^T = K Q (swapped): lane holds S[kv = gh*64+jt*16+q4*4+r][q = ..+i*16+n16] ----
        f32x4 st[2][4];
        __builtin_amdgcn_s_setprio(1);
#pragma unroll
        for (int jt = 0; jt < 4; ++jt) {
            bf16x8 kf0 = *(const bf16x8*)&kbuf[(jt * 16 + n16) * 64 + xo0];
            bf16x8 kf1 = *(const bf16x8*)&kbuf[(jt * 16 + n16) * 64 + xo1];
#pragma unroll
            for (int i = 0; i < 2; ++i) {
                f32x4 s = {};
                s = __builtin_amdgcn_mfma_f32_16x16x32_bf16(kf0, qf[i][0], s, 0, 0, 0);
                s = __builtin_amdgcn_mfma_f32_16x16x32_bf16(kf1, qf[i][1], s, 0, 0, 0);
                st[i][jt] = s;
            }
        }
        __builtin_amdgcn_s_setprio(0);

        // ---- causal mask on the diagonal tile (kv > q) ----
        if (gh == my_last) {
#pragma unroll
            for (int i = 0; i < 2; ++i) {
                int qg = q0 + w * 32 + i * 16 + n16;
#pragma unroll
                for (int jt = 0; jt < 4; ++jt) {
                    int kvb = gh * 64 + jt * 16 + q4 * 4;
#pragma unroll
                    for (int r = 0; r < 4; ++r)
                        if (kvb + r > qg) st[i][jt][r] = -1e30f;
                }
            }
        }

        // ---- exp (raw v_exp_f32 path) ----
#pragma unroll
        for (int i = 0; i < 2; ++i)
#pragma unroll
            for (int jt = 0; jt < 4; ++jt)
#pragma unroll
                for (int r = 0; r < 4; ++r)
                    st[i][jt][r] = EXPFN(st[i][jt][r]);

        // ---- P: pack in-lane (kv-consecutive) -> 8 ds_write_b64 ----
#pragma unroll
        for (int i = 0; i < 2; ++i) {
            bf16_t* pr = &ps[w][(i * 16 + n16) * PLD];
#pragma unroll
            for (int jt = 0; jt < 4; ++jt) {
                u32x2 pw;
                pw[0] = cvt_pk_bf16(st[i][jt][0], st[i][jt][1]);
                pw[1] = cvt_pk_bf16(st[i][jt][2], st[i][jt][3]);
                *(u32x2*)&pr[jt * 16 + q4 * 4] = pw;
            }
        }

        bf16x8 pf[2][2];
#pragma unroll
        for (int i = 0; i < 2; ++i) {
            const bf16_t* pr = &ps[w][(i * 16 + n16) * PLD];
            pf[i][0] = *(const bf16x8*)&pr[q4 * 8];
            pf[i][1] = *(const bf16x8*)&pr[32 + q4 * 8];
        }

        __builtin_amdgcn_s_setprio(1);
        // ---- l += row-sum(P) via ones-MFMA ----
#pragma unroll
        for (int i = 0; i < 2; ++i) {
            acc_l[i] = __builtin_amdgcn_mfma_f32_16x16x32_bf16(pf[i][0], ones8, acc_l[i], 0, 0, 0);
            acc_l[i] = __builtin_amdgcn_mfma_f32_16x16x32_bf16(pf[i][1], ones8, acc_l[i], 0, 0, 0);
        }
        // ---- O += P V ----
#pragma unroll
        for (int jd = 0; jd < 4; ++jd) {
            bf16x8 vf0 = *(const bf16x8*)&vbuf[(jd * 16 + n16) * 64 + xo0];
            bf16x8 vf1 = *(const bf16x8*)&vbuf[(jd * 16 + n16) * 64 + xo1];
#pragma unroll
            for (int i = 0; i < 2; ++i) {
                acc[i][jd] = __builtin_amdgcn_mfma_f32_16x16x32_bf16(pf[i][0], vf0, acc[i][jd], 0, 0, 0);
                acc[i][jd] = __builtin_amdgcn_mfma_f32_16x16x32_bf16(pf[i][1], vf1, acc[i][jd], 0, 0, 0);
            }
        }
        __builtin_amdgcn_s_setprio(0);
    };

    // ---- 2-phase pipelined main loop (gh-count = 2qt+2, always even) ----
    stage(0, kb0, vb0);
    __syncthreads();
    for (int gh = 0; gh <= ghmax; gh += 2) {
        if (gh < ghmax) stage(gh + 1, kb1, vb1);
        if (gh <= my_last) compute(gh, kb0, vb0);
        __syncthreads();
        if (gh + 1 < ghmax) stage(gh + 2, kb0, vb0);
        if (gh + 1 <= my_last) compute(gh + 1, kb1, vb1);
        __syncthreads();
    }

    // ---- normalize + store ----
#pragma unroll
    for (int i = 0; i < 2; ++i) {
        float linv[4];
#pragma unroll
        for (int r = 0; r < 4; ++r) linv[r] = 1.0f / acc_l[i][r];
#pragma unroll
        for (int jd = 0; jd < 4; ++jd)
#pragma unroll
            for (int r = 0; r < 4; ++r) {
                int rowg = q0 + w * 32 + i * 16 + q4 * 4 + r;
                Om[(size_t)rowg * HID + h * HD + jd * 16 + n16] = (bf16_t)(acc[i][jd][r] * linv[r]);
            }
    }
}

// ---------------------------------------------------------------------------
extern "C" void kernel_launch(void* const* d_in, const int* in_sizes, int n_in,
                              void* d_out, int out_size, void* d_ws, size_t ws_size,
                              hipStream_t stream)
{
    const float* X  = (const float*)d_in[0];
    const float* Wq = (const float*)d_in[1];
    const float* Wk = (const float*)d_in[2];
    const float* Wv = (const float*)d_in[3];
    const float* Wo = (const float*)d_in[4];
    float* out = (float*)d_out;

    bf16_t* Xb  = (bf16_t*)d_ws;                      // [SEQ][HID]     8 MB
    bf16_t* Wqb = Xb  + (size_t)NX;                   // [2048][2048]   8 MB
    bf16_t* Wkb = Wqb + (size_t)NWQ;                  // [512][2048]    2 MB
    bf16_t* Wvb = Wkb + (size_t)NWK;                  // [512][2048]    2 MB
    bf16_t* Wob = Wvb + (size_t)NWV;                  // [2048][2048]   8 MB
    bf16_t* Qb  = Wob + (size_t)NWO;                  // [SEQ][NH*HD]   8 MB (pre-scaled QSCALE)
    bf16_t* Kb  = Qb  + (size_t)SEQ * (NH * HD);      // [SEQ][KVDIM]   2 MB
    bf16_t* Vt  = Kb  + (size_t)SEQ * KVDIM;          // [KVDIM][SEQ]   2 MB
    bf16_t* Ob  = Vt  + (size_t)SEQ * KVDIM;          // [SEQ][NH*HD]   8 MB

    // one-shot fp32 -> bf16 conversion of all operands
    cvt_all<<<dim3((NTOT / 8 + 255) / 256), dim3(256), 0, stream>>>(X, Wq, Wk, Wv, Wo, Xb, Wqb, Wkb, Wvb, Wob);

    // fused QKV projection + RoPE (128x128 tiles, 512 threads, 4 waves/SIMD)
    qkv_gemm<<<dim3(SEQ / 128, (NH * HD + 2 * KVDIM) / 128), dim3(512), 0, stream>>>(Xb, Wqb, Wkb, Wvb, Qb, Kb, Vt);

    // causal GQA attention (Bq=128, 512 blocks, swapped-QK + packed P)
    attn_mfma<<<dim3((SEQ / 128) * NH), dim3(256), 0, stream>>>(Qb, Kb, Vt, Ob);

    // output projection (128x128 tiles, 512 threads, grid 256 = 1/CU)
    o_gemm<<<dim3(SEQ / 128, HID / 128), dim3(512), 0, stream>>>(Ob, Wob, out);
}

// Round 10
// 184.328 us; speedup vs baseline: 1.0660x; 1.0110x over previous
//
#include <hip/hip_runtime.h>
#include <hip/hip_bf16.h>
#include <cstdint>
#include <cstddef>

// Problem constants
#define SEQ   2048
#define HID   2048
#define NH    32
#define NKVH  8
#define HD    64
#define KVDIM (NKVH * HD)   // 512

typedef __bf16 bf16_t;
typedef __bf16 bf16x8 __attribute__((ext_vector_type(8)));
typedef float  f32x4  __attribute__((ext_vector_type(4)));
typedef unsigned int u32x2 __attribute__((ext_vector_type(2)));

// log2(10000)/32  (RoPE: theta^(-d/32) = exp2(-d*L))
#define ROPE_L 0.4152410118609203f

#if __has_builtin(__builtin_amdgcn_exp2f)
#define QSCALE 0.18033688011112043f
#define EXPFN(x) __builtin_amdgcn_exp2f(x)
#else
#define QSCALE 0.125f
#define EXPFN(x) __expf(x)
#endif

// counted-vmcnt barrier primitives (T4): wave waits for its OLDEST stage's
// loads only; the next stage's loads stay in flight across the barrier.
#define WAITV4  do { asm volatile("s_waitcnt vmcnt(4)" ::: "memory"); \
                     __builtin_amdgcn_sched_barrier(0); \
                     __builtin_amdgcn_s_barrier(); } while (0)
#define WAITV0  do { asm volatile("s_waitcnt vmcnt(0)" ::: "memory"); \
                     __builtin_amdgcn_sched_barrier(0); \
                     __builtin_amdgcn_s_barrier(); } while (0)
#define BAR     __builtin_amdgcn_s_barrier()

__device__ __forceinline__ bf16x8 load8(const float* p) {
    const float4 lo = *(const float4*)p;
    const float4 hi = *(const float4*)(p + 4);
    bf16x8 r;
    r[0] = (bf16_t)lo.x; r[1] = (bf16_t)lo.y; r[2] = (bf16_t)lo.z; r[3] = (bf16_t)lo.w;
    r[4] = (bf16_t)hi.x; r[5] = (bf16_t)hi.y; r[6] = (bf16_t)hi.z; r[7] = (bf16_t)hi.w;
    return r;
}

// async global->LDS, 16B per lane; LDS dest = wave-uniform base + lane*16
__device__ __forceinline__ void load_lds16(const bf16_t* g, bf16_t* l) {
    __builtin_amdgcn_global_load_lds((const __attribute__((address_space(1))) void*)g,
                                     (__attribute__((address_space(3))) void*)l,
                                     16, 0, 0);
}

// pack two f32 -> one dword of 2 bf16 (no builtin on gfx950; T12 recipe, m240)
__device__ __forceinline__ unsigned int cvt_pk_bf16(float lo, float hi) {
    unsigned int r;
    asm("v_cvt_pk_bf16_f32 %0, %1, %2" : "=v"(r) : "v"(lo), "v"(hi));
    return r;
}

// ---------------------------------------------------------------------------
// One-shot fp32 -> bf16 conversion of all GEMM operands.
// ---------------------------------------------------------------------------
#define NX  (SEQ * HID)          // 4M
#define NWQ (NH * HD * HID)      // 4M
#define NWK (KVDIM * HID)        // 1M
#define NWV (KVDIM * HID)        // 1M
#define NWO (HID * NH * HD)      // 4M
#define NTOT (NX + NWQ + NWK + NWV + NWO)   // 14M

__global__ __launch_bounds__(256) void cvt_all(const float* __restrict__ X,
                                               const float* __restrict__ Wq,
                                               const float* __restrict__ Wk,
                                               const float* __restrict__ Wv,
                                               const float* __restrict__ Wo,
                                               bf16_t* __restrict__ Xb,
                                               bf16_t* __restrict__ Wqb,
                                               bf16_t* __restrict__ Wkb,
                                               bf16_t* __restrict__ Wvb,
                                               bf16_t* __restrict__ Wob)
{
    size_t i = ((size_t)blockIdx.x * 256 + threadIdx.x) * 8;
    if (i >= NTOT) return;
    const size_t E0 = NX, E1 = E0 + NWQ, E2 = E1 + NWK, E3 = E2 + NWV;
    const float* s; bf16_t* d; size_t off;
    if (i < E0)      { s = X;  d = Xb;  off = i; }
    else if (i < E1) { s = Wq; d = Wqb; off = i - E0; }
    else if (i < E2) { s = Wk; d = Wkb; off = i - E1; }
    else if (i < E3) { s = Wv; d = Wvb; off = i - E2; }
    else             { s = Wo; d = Wob; off = i - E3; }
    *(bf16x8*)(d + off) = load8(s + off);
}

// ---------------------------------------------------------------------------
// Swizzled-tile convention (T2, both-sides, rule #21):
//   LDS tile = [rows][64] bf16, 128B rows.  Physical 16B slot s of row r
//   holds LOGICAL k-group (s ^ (r&7)).  Staging: linear LDS dest, per-lane
//   pre-swizzled global source.  Reads: slot G ^ (r&7).
//
// XCD swizzle (T1, R10): FETCH_SIZE showed 384 MB of panel traffic vs
// 20 MB compulsory — blocks sharing a panel sat on different XCD L2s
// (round-robin dispatch).  1D grid; xcd = bid&7, j = bid>>3 indexes a
// contiguous 2D chunk (8m x 6n for qkv, 8m x 4n for o) per XCD: the
// 48 concurrent blocks of an XCD sweep K in near-lockstep over a shared
// 8A+6B panel window -> L2 coalesces the 6-8x re-reads.
// ---------------------------------------------------------------------------

// ---------------------------------------------------------------------------
// Fused QKV projection + RoPE, 128x128 tiles, 512 threads (8 waves, 4x2
// grid of 32x64 wave-tiles), counted-vmcnt pipeline, XCD-chunked blocks.
// ---------------------------------------------------------------------------
__global__ __launch_bounds__(512, 4) void qkv_gemm(const bf16_t* __restrict__ Xb,
                                                   const bf16_t* __restrict__ Wqb,
                                                   const bf16_t* __restrict__ Wkb,
                                                   const bf16_t* __restrict__ Wvb,
                                                   bf16_t* __restrict__ Qb,
                                                   bf16_t* __restrict__ Kb,
                                                   bf16_t* __restrict__ Vt)
{
    __shared__ alignas(16) bf16_t sa0[128 * 64], sa1[128 * 64];   // 16KB each
    __shared__ alignas(16) bf16_t sb0[128 * 64], sb1[128 * 64];   // 16KB each
    const int t = threadIdx.x;
    const int lane = t & 63;
    const int w  = t >> 6;               // 0..7
    const int n16 = lane & 15;
    const int q4  = lane >> 4;
    const int wm = (w >> 1) * 32;        // wave tile origin in M (0,32,64,96)
    const int wn = (w & 1) * 64;         // wave tile origin in N (head-aligned)
    f32x4 acc[2][4] = {};

    // ---- T1 XCD-chunked block swizzle: grid 384 = 8 XCDs x (8m x 6n) ----
    const int bid = blockIdx.x;
    const int xcd = bid & 7;
    const int j   = bid >> 3;                    // 0..47
    const int m0 = ((xcd & 1) * 8 + (j & 7)) * 128;     // m-tile 0..15
    const int n0 = ((xcd >> 1) * 6 + (j >> 3)) * 128;   // n-tile 0..23

    const bf16_t* B;
    int mode, nc;
    if (n0 < NH * HD)              { B = Wqb + (size_t)n0 * HID;                     mode = 0; nc = n0; }
    else if (n0 < NH * HD + KVDIM) { B = Wkb + (size_t)(n0 - NH * HD) * HID;         mode = 1; nc = n0 - NH * HD; }
    else                           { B = Wvb + (size_t)(n0 - NH * HD - KVDIM) * HID; mode = 2; nc = n0 - NH * HD - KVDIM; }

    const int lrow8 = lane >> 3;                 // 0..7 (row within 8-row chunk)
    const int lgrp  = (lane & 7) ^ lrow8;        // pre-swizzled source col-group
    const bf16_t* ag = Xb + (size_t)(m0 + w * 16 + lrow8) * HID + lgrp * 8;
    const bf16_t* bg = B  + (size_t)(w * 16 + lrow8) * HID + lgrp * 8;

    auto stage = [&](bf16_t* da, bf16_t* db, int k0) {
        // wave w covers A rows [w*16, w*16+16) and B rows [w*16, w*16+16)
        load_lds16(ag + k0,                      da + (w * 16) * 64);
        load_lds16(ag + (size_t)8 * HID + k0,    da + (w * 16 + 8) * 64);
        load_lds16(bg + k0,                      db + (w * 16) * 64);
        load_lds16(bg + (size_t)8 * HID + k0,    db + (w * 16 + 8) * 64);
    };
    auto mma_step = [&](const bf16_t* sa, const bf16_t* sb) {
#pragma unroll
        for (int kk = 0; kk < 2; ++kk) {
            const int xo = ((kk * 4 + q4) ^ (n16 & 7)) * 8;
            bf16x8 bfrag[4], afrag[2];
#pragma unroll
            for (int j2 = 0; j2 < 4; ++j2)
                bfrag[j2] = *(const bf16x8*)&sb[(wn + j2 * 16 + n16) * 64 + xo];
#pragma unroll
            for (int i = 0; i < 2; ++i)
                afrag[i] = *(const bf16x8*)&sa[(wm + i * 16 + n16) * 64 + xo];
#pragma unroll
            for (int i = 0; i < 2; ++i)
#pragma unroll
                for (int j2 = 0; j2 < 4; ++j2)
                    acc[i][j2] = __builtin_amdgcn_mfma_f32_16x16x32_bf16(afrag[i], bfrag[j2], acc[i][j2], 0, 0, 0);
        }
    };

    // 32 stages of BK=64.  Prologue: stages 0,1.  Loop t issues stage t+2.
    stage(sa0, sb0, 0);
    stage(sa1, sb1, 64);
#pragma unroll 1
    for (int tt = 0; tt < 30; tt += 2) {
        WAITV4;
        mma_step(sa0, sb0);
        BAR;
        stage(sa0, sb0, (tt + 2) * 64);
        WAITV4;
        mma_step(sa1, sb1);
        BAR;
        stage(sa1, sb1, (tt + 3) * 64);
    }
    WAITV4;
    mma_step(sa0, sb0);      // stage 30
    BAR;
    WAITV0;
    mma_step(sa1, sb1);      // stage 31

    if (mode < 2) {
        // ---- RoPE in registers: wave covers one head (wn mult of HD) ----
#pragma unroll
        for (int jt = 0; jt < 2; ++jt) {
            float dd = (float)(jt * 16 + n16);
            float inv = exp2f(-dd * ROPE_L);
#pragma unroll
            for (int i = 0; i < 2; ++i) {
#pragma unroll
                for (int r = 0; r < 4; ++r) {
                    int pos = m0 + wm + i * 16 + q4 * 4 + r;
                    float ang = (float)pos * inv;
                    float sn, cs;
                    sincosf(ang, &sn, &cs);
                    float x1 = acc[i][jt][r], x2 = acc[i][jt + 2][r];
                    acc[i][jt][r]     = x1 * cs - x2 * sn;
                    acc[i][jt + 2][r] = x2 * cs + x1 * sn;
                }
            }
        }
        const float osc = (mode == 0) ? QSCALE : 1.0f;
        bf16_t* dst = (mode == 0) ? Qb : Kb;
        const int ld = (mode == 0) ? NH * HD : KVDIM;
#pragma unroll
        for (int i = 0; i < 2; ++i)
#pragma unroll
            for (int j2 = 0; j2 < 4; ++j2) {
                int row = m0 + wm + i * 16 + q4 * 4;
                int col = nc + wn + j2 * 16 + n16;
#pragma unroll
                for (int r = 0; r < 4; ++r)
                    dst[(size_t)(row + r) * ld + col] = (bf16_t)(acc[i][j2][r] * osc);
            }
    } else {
        // ---- V: store transposed ----
#pragma unroll
        for (int i = 0; i < 2; ++i)
#pragma unroll
            for (int j2 = 0; j2 < 4; ++j2) {
                int row = m0 + wm + i * 16 + q4 * 4;
                int col = nc + wn + j2 * 16 + n16;
#pragma unroll
                for (int r = 0; r < 4; ++r)
                    Vt[(size_t)col * SEQ + row + r] = (bf16_t)acc[i][j2][r];
            }
    }
}

// ---------------------------------------------------------------------------
// O projection: 512-thread 128x128 blocks, grid 256 (1/CU), counted-vmcnt,
// XCD-chunked 8m x 4n blocks.
// ---------------------------------------------------------------------------
__global__ __launch_bounds__(512, 4) void o_gemm(const bf16_t* __restrict__ A,
                                                 const bf16_t* __restrict__ Bw,
                                                 float* __restrict__ C)
{
    __shared__ alignas(16) bf16_t sa0[128 * 64], sa1[128 * 64];
    __shared__ alignas(16) bf16_t sb0[128 * 64], sb1[128 * 64];
    const int t = threadIdx.x;
    const int lane = t & 63;
    const int w  = t >> 6;
    const int n16 = lane & 15;
    const int q4  = lane >> 4;
    const int wm = (w >> 1) * 32;
    const int wn = (w & 1) * 64;
    f32x4 acc[2][4] = {};

    // ---- T1 XCD-chunked swizzle: grid 256 = 8 XCDs x (8m x 4n) ----
    const int bid = blockIdx.x;
    const int xcd = bid & 7;
    const int j   = bid >> 3;                    // 0..31
    const int m0 = ((xcd & 1) * 8 + (j & 7)) * 128;     // m-tile 0..15
    const int n0 = ((xcd >> 1) * 4 + (j >> 3)) * 128;   // n-tile 0..15

    const int lrow8 = lane >> 3;
    const int lgrp  = (lane & 7) ^ lrow8;
    const bf16_t* ag = A  + (size_t)(m0 + w * 16 + lrow8) * HID + lgrp * 8;
    const bf16_t* bg = Bw + (size_t)(n0 + w * 16 + lrow8) * HID + lgrp * 8;

    auto stage = [&](bf16_t* da, bf16_t* db, int k0) {
        load_lds16(ag + k0,                      da + (w * 16) * 64);
        load_lds16(ag + (size_t)8 * HID + k0,    da + (w * 16 + 8) * 64);
        load_lds16(bg + k0,                      db + (w * 16) * 64);
        load_lds16(bg + (size_t)8 * HID + k0,    db + (w * 16 + 8) * 64);
    };
    auto mma_step = [&](const bf16_t* sa, const bf16_t* sb) {
#pragma unroll
        for (int kk = 0; kk < 2; ++kk) {
            const int xo = ((kk * 4 + q4) ^ (n16 & 7)) * 8;
            bf16x8 bfrag[4], afrag[2];
#pragma unroll
            for (int j2 = 0; j2 < 4; ++j2)
                bfrag[j2] = *(const bf16x8*)&sb[(wn + j2 * 16 + n16) * 64 + xo];
#pragma unroll
            for (int i = 0; i < 2; ++i)
                afrag[i] = *(const bf16x8*)&sa[(wm + i * 16 + n16) * 64 + xo];
#pragma unroll
            for (int i = 0; i < 2; ++i)
#pragma unroll
                for (int j2 = 0; j2 < 4; ++j2)
                    acc[i][j2] = __builtin_amdgcn_mfma_f32_16x16x32_bf16(afrag[i], bfrag[j2], acc[i][j2], 0, 0, 0);
        }
    };

    stage(sa0, sb0, 0);
    stage(sa1, sb1, 64);
#pragma unroll 1
    for (int tt = 0; tt < 30; tt += 2) {
        WAITV4;
        mma_step(sa0, sb0);
        BAR;
        stage(sa0, sb0, (tt + 2) * 64);
        WAITV4;
        mma_step(sa1, sb1);
        BAR;
        stage(sa1, sb1, (tt + 3) * 64);
    }
    WAITV4;
    mma_step(sa0, sb0);
    BAR;
    WAITV0;
    mma_step(sa1, sb1);

#pragma unroll
    for (int i = 0; i < 2; ++i)
#pragma unroll
        for (int j2 = 0; j2 < 4; ++j2) {
            int row = m0 + wm + i * 16 + q4 * 4;
            int col = n0 + wn + j2 * 16 + n16;
#pragma unroll
            for (int r = 0; r < 4; ++r)
                C[(size_t)(row + r) * HID + col] = acc[i][j2][r];
        }
}

// ---------------------------------------------------------------------------
// MFMA causal flash attention — unchanged from R7/R8/R9 (swapped-QK + packed P).
// ---------------------------------------------------------------------------
#define PLD 72   // P staging row stride (144B: 16B-aligned rows, conflict-min reads)

__global__ __launch_bounds__(256, 3) void attn_mfma(const bf16_t* __restrict__ Qm,
                                                    const bf16_t* __restrict__ Km,
                                                    const bf16_t* __restrict__ Vt,
                                                    bf16_t* __restrict__ Om)
{
    const int bid = blockIdx.x;
    const int h   = bid & (NH - 1);
    const int qt  = (bid < (SEQ / 128) * NH / 2)
                      ? (SEQ / 128 - 1 - (bid >> 5))
                      : ((bid - (SEQ / 128) * NH / 2) >> 5);
    const int q0  = qt * 128;
    const int kvh = h >> 2;            // H/KVH = 4
    const int t    = threadIdx.x;
    const int w    = t >> 6;
    const int lane = t & 63;
    const int n16  = lane & 15;
    const int q4   = lane >> 4;

    __shared__ alignas(16) bf16_t kb0[64 * 64], kb1[64 * 64];   // K: [kv][d] swz, 8KB each
    __shared__ alignas(16) bf16_t vb0[64 * 64], vb1[64 * 64];   // V: [d][kv] swz
    __shared__ alignas(16) bf16_t ps[4][32 * PLD];              // per-wave P: [q][kv]

    // Q fragments in registers: rows q0 + w*32 + i*16 + n16 (B-layout for swapped QK)
    bf16x8 qf[2][2];
#pragma unroll
    for (int i = 0; i < 2; ++i) {
        const bf16_t* qp = Qm + (size_t)(q0 + w * 32 + i * 16 + n16) * HID + h * HD;
        qf[i][0] = *(const bf16x8*)(qp + q4 * 8);
        qf[i][1] = *(const bf16x8*)(qp + 32 + q4 * 8);
    }

    f32x4 acc[2][4] = {};
    f32x4 acc_l[2] = {};                 // row-sums of P via ones-MFMA
    const bf16_t one = (bf16_t)1.0f;
    const bf16x8 ones8 = {one, one, one, one, one, one, one, one};

    // staging source addresses (pre-swizzled global col-group, T2 rule #21)
    const int lrow8 = lane >> 3;                 // 0..7
    const int lgrp  = (lane & 7) ^ lrow8;        // source 16B group
    const bf16_t* kgs = Km + (size_t)kvh * HD + (size_t)lrow8 * KVDIM + lgrp * 8;
    const bf16_t* vgs = Vt + (size_t)(kvh * HD + lrow8) * SEQ + lgrp * 8;

    // swizzled fragment-read offsets: logical group g at slot g^(r&7)
    const int rx  = n16 & 7;
    const int xo0 = (q4 ^ rx) * 8;               // groups 0..3
    const int xo1 = ((q4 + 4) ^ rx) * 8;         // groups 4..7

    const int ghmax  = 2 * qt + 1;               // last 64-kv tile staged (odd)
    const int my_last = 2 * qt + (w >> 1);       // last 64-kv tile this wave computes

    auto stage = [&](int gh, bf16_t* kb, bf16_t* vb) {
        const int k0 = gh * 64;
        load_lds16(kgs + (size_t)(k0 + w * 8)      * KVDIM, kb + (w * 8)      * 64);
        load_lds16(kgs + (size_t)(k0 + w * 8 + 32) * KVDIM, kb + (w * 8 + 32) * 64);
        load_lds16(vgs + (size_t)(w * 8)      * SEQ + k0,   vb + (w * 8)      * 64);
        load_lds16(vgs + (size_t)(w * 8 + 32) * SEQ + k0,   vb + (w * 8 + 32) * 64);
    };

    auto compute = [&](int gh, const bf16_t* kbuf, const bf16_t* vbuf) {
        // ---- S^T = K Q (swapped): lane holds S[kv = gh*64+jt*16+q4*4+r][q = ..+i*16+n16] ----
        f32x4 st[2][4];
        __builtin_amdgcn_s_setprio(1);
#pragma unroll
        for (int jt = 0; jt < 4; ++jt) {
            bf16x8 kf0 = *(const bf16x8*)&kbuf[(jt * 16 + n16) * 64 + xo0];
            bf16x8 kf1 = *(const bf16x8*)&kbuf[(jt * 16 + n16) * 64 + xo1];
#pragma unroll
            for (int i = 0; i < 2; ++i) {
                f32x4 s = {};
                s = __builtin_amdgcn_mfma_f32_16x16x32_bf16(kf0, qf[i][0], s, 0, 0, 0);
                s = __builtin_amdgcn_mfma_f32_16x16x32_bf16(kf1, qf[i][1], s, 0, 0, 0);
                st[i][jt] = s;
            }
        }
        __builtin_amdgcn_s_setprio(0);

        // ---- causal mask on the diagonal tile (kv > q) ----
        if (gh == my_last) {
#pragma unroll
            for (int i = 0; i < 2; ++i) {
                int qg = q0 + w * 32 + i * 16 + n16;
#pragma unroll
                for (int jt = 0; jt < 4; ++jt) {
                    int kvb = gh * 64 + jt * 16 + q4 * 4;
#pragma unroll
                    for (int r = 0; r < 4; ++r)
                        if (kvb + r > qg) st[i][jt][r] = -1e30f;
                }
            }
        }

        // ---- exp (raw v_exp_f32 path) ----
#pragma unroll
        for (int i = 0; i < 2; ++i)
#pragma unroll
            for (int jt = 0; jt < 4; ++jt)
#pragma unroll
                for (int r = 0; r < 4; ++r)
                    st[i][jt][r] = EXPFN(st[i][jt][r]);

        // ---- P: pack in-lane (kv-consecutive) -> 8 ds_write_b64 ----
#pragma unroll
        for (int i = 0; i < 2; ++i) {
            bf16_t* pr = &ps[w][(i * 16 + n16) * PLD];
#pragma unroll
            for (int jt = 0; jt < 4; ++jt) {
                u32x2 pw;
                pw[0] = cvt_pk_bf16(st[i][jt][0], st[i][jt][1]);
                pw[1] = cvt_pk_bf16(st[i][jt][2], st[i][jt][3]);
                *(u32x2*)&pr[jt * 16 + q4 * 4] = pw;
            }
        }

        bf16x8 pf[2][2];
#pragma unroll
        for (int i = 0; i < 2; ++i) {
            const bf16_t* pr = &ps[w][(i * 16 + n16) * PLD];
            pf[i][0] = *(const bf16x8*)&pr[q4 * 8];
            pf[i][1] = *(const bf16x8*)&pr[32 + q4 * 8];
        }

        __builtin_amdgcn_s_setprio(1);
        // ---- l += row-sum(P) via ones-MFMA ----
#pragma unroll
        for (int i = 0; i < 2; ++i) {
            acc_l[i] = __builtin_amdgcn_mfma_f32_16x16x32_bf16(pf[i][0], ones8, acc_l[i], 0, 0, 0);
            acc_l[i] = __builtin_amdgcn_mfma_f32_16x16x32_bf16(pf[i][1], ones8, acc_l[i], 0, 0, 0);
        }
        // ---- O += P V ----
#pragma unroll
        for (int jd = 0; jd < 4; ++jd) {
            bf16x8 vf0 = *(const bf16x8*)&vbuf[(jd * 16 + n16) * 64 + xo0];
            bf16x8 vf1 = *(const bf16x8*)&vbuf[(jd * 16 + n16) * 64 + xo1];
#pragma unroll
            for (int i = 0; i < 2; ++i) {
                acc[i][jd] = __builtin_amdgcn_mfma_f32_16x16x32_bf16(pf[i][0], vf0, acc[i][jd], 0, 0, 0);
                acc[i][jd] = __builtin_amdgcn_mfma_f32_16x16x32_bf16(pf[i][1], vf1, acc[i][jd], 0, 0, 0);
            }
        }
        __builtin_amdgcn_s_setprio(0);
    };

    // ---- 2-phase pipelined main loop (gh-count = 2qt+2, always even) ----
    stage(0, kb0, vb0);
    __syncthreads();
    for (int gh = 0; gh <= ghmax; gh += 2) {
        if (gh < ghmax) stage(gh + 1, kb1, vb1);
        if (gh <= my_last) compute(gh, kb0, vb0);
        __syncthreads();
        if (gh + 1 < ghmax) stage(gh + 2, kb0, vb0);
        if (gh + 1 <= my_last) compute(gh + 1, kb1, vb1);
        __syncthreads();
    }

    // ---- normalize + store ----
#pragma unroll
    for (int i = 0; i < 2; ++i) {
        float linv[4];
#pragma unroll
        for (int r = 0; r < 4; ++r) linv[r] = 1.0f / acc_l[i][r];
#pragma unroll
        for (int jd = 0; jd < 4; ++jd)
#pragma unroll
            for (int r = 0; r < 4; ++r) {
                int rowg = q0 + w * 32 + i * 16 + q4 * 4 + r;
                Om[(size_t)rowg * HID + h * HD + jd * 16 + n16] = (bf16_t)(acc[i][jd][r] * linv[r]);
            }
    }
}

// ---------------------------------------------------------------------------
extern "C" void kernel_launch(void* const* d_in, const int* in_sizes, int n_in,
                              void* d_out, int out_size, void* d_ws, size_t ws_size,
                              hipStream_t stream)
{
    const float* X  = (const float*)d_in[0];
    const float* Wq = (const float*)d_in[1];
    const float* Wk = (const float*)d_in[2];
    const float* Wv = (const float*)d_in[3];
    const float* Wo = (const float*)d_in[4];
    float* out = (float*)d_out;

    bf16_t* Xb  = (bf16_t*)d_ws;                      // [SEQ][HID]     8 MB
    bf16_t* Wqb = Xb  + (size_t)NX;                   // [2048][2048]   8 MB
    bf16_t* Wkb = Wqb + (size_t)NWQ;                  // [512][2048]    2 MB
    bf16_t* Wvb = Wkb + (size_t)NWK;                  // [512][2048]    2 MB
    bf16_t* Wob = Wvb + (size_t)NWV;                  // [2048][2048]   8 MB
    bf16_t* Qb  = Wob + (size_t)NWO;                  // [SEQ][NH*HD]   8 MB (pre-scaled QSCALE)
    bf16_t* Kb  = Qb  + (size_t)SEQ * (NH * HD);      // [SEQ][KVDIM]   2 MB
    bf16_t* Vt  = Kb  + (size_t)SEQ * KVDIM;          // [KVDIM][SEQ]   2 MB
    bf16_t* Ob  = Vt  + (size_t)SEQ * KVDIM;          // [SEQ][NH*HD]   8 MB

    // one-shot fp32 -> bf16 conversion of all operands
    cvt_all<<<dim3((NTOT / 8 + 255) / 256), dim3(256), 0, stream>>>(X, Wq, Wk, Wv, Wo, Xb, Wqb, Wkb, Wvb, Wob);

    // fused QKV projection + RoPE (128x128 tiles, XCD-chunked 1D grid of 384)
    qkv_gemm<<<dim3(16 * 24), dim3(512), 0, stream>>>(Xb, Wqb, Wkb, Wvb, Qb, Kb, Vt);

    // causal GQA attention (Bq=128, 512 blocks, swapped-QK + packed P)
    attn_mfma<<<dim3((SEQ / 128) * NH), dim3(256), 0, stream>>>(Qb, Kb, Vt, Ob);

    // output projection (128x128 tiles, XCD-chunked 1D grid of 256)
    o_gemm<<<dim3(16 * 16), dim3(512), 0, stream>>>(Ob, Wob, out);
}

// Round 11
// 180.912 us; speedup vs baseline: 1.0861x; 1.0189x over previous
//
#include <hip/hip_runtime.h>
#include <hip/hip_bf16.h>
#include <cstdint>
#include <cstddef>

// Problem constants
#define SEQ   2048
#define HID   2048
#define NH    32
#define NKVH  8
#define HD    64
#define KVDIM (NKVH * HD)   // 512

typedef __bf16 bf16_t;
typedef __bf16 bf16x8 __attribute__((ext_vector_type(8)));
typedef float  f32x4  __attribute__((ext_vector_type(4)));
typedef unsigned int u32x2 __attribute__((ext_vector_type(2)));
typedef unsigned int u32x4 __attribute__((ext_vector_type(4)));

// log2(10000)/32  (RoPE: theta^(-d/32) = exp2(-d*L))
#define ROPE_L 0.4152410118609203f

#if __has_builtin(__builtin_amdgcn_exp2f)
#define QSCALE 0.18033688011112043f
#define EXPFN(x) __builtin_amdgcn_exp2f(x)
#else
#define QSCALE 0.125f
#define EXPFN(x) __expf(x)
#endif

// counted-vmcnt barrier primitives (T4): wave waits for its OLDEST stage's
// loads only; the next stage's loads stay in flight across the barrier.
#define WAITV4  do { asm volatile("s_waitcnt vmcnt(4)" ::: "memory"); \
                     __builtin_amdgcn_sched_barrier(0); \
                     __builtin_amdgcn_s_barrier(); } while (0)
#define WAITV0  do { asm volatile("s_waitcnt vmcnt(0)" ::: "memory"); \
                     __builtin_amdgcn_sched_barrier(0); \
                     __builtin_amdgcn_s_barrier(); } while (0)
#define BAR     __builtin_amdgcn_s_barrier()

__device__ __forceinline__ bf16x8 load8(const float* p) {
    const float4 lo = *(const float4*)p;
    const float4 hi = *(const float4*)(p + 4);
    bf16x8 r;
    r[0] = (bf16_t)lo.x; r[1] = (bf16_t)lo.y; r[2] = (bf16_t)lo.z; r[3] = (bf16_t)lo.w;
    r[4] = (bf16_t)hi.x; r[5] = (bf16_t)hi.y; r[6] = (bf16_t)hi.z; r[7] = (bf16_t)hi.w;
    return r;
}

// async global->LDS, 16B per lane; LDS dest = wave-uniform base + lane*16
__device__ __forceinline__ void load_lds16(const bf16_t* g, bf16_t* l) {
    __builtin_amdgcn_global_load_lds((const __attribute__((address_space(1))) void*)g,
                                     (__attribute__((address_space(3))) void*)l,
                                     16, 0, 0);
}

// pack two f32 -> one dword of 2 bf16 (no builtin on gfx950; T12 recipe, m240)
__device__ __forceinline__ unsigned int cvt_pk_bf16(float lo, float hi) {
    unsigned int r;
    asm("v_cvt_pk_bf16_f32 %0, %1, %2" : "=v"(r) : "v"(lo), "v"(hi));
    return r;
}

// ---------------------------------------------------------------------------
// One-shot fp32 -> bf16 conversion of all GEMM operands.
// ---------------------------------------------------------------------------
#define NX  (SEQ * HID)          // 4M
#define NWQ (NH * HD * HID)      // 4M
#define NWK (KVDIM * HID)        // 1M
#define NWV (KVDIM * HID)        // 1M
#define NWO (HID * NH * HD)      // 4M
#define NTOT (NX + NWQ + NWK + NWV + NWO)   // 14M

__global__ __launch_bounds__(256) void cvt_all(const float* __restrict__ X,
                                               const float* __restrict__ Wq,
                                               const float* __restrict__ Wk,
                                               const float* __restrict__ Wv,
                                               const float* __restrict__ Wo,
                                               bf16_t* __restrict__ Xb,
                                               bf16_t* __restrict__ Wqb,
                                               bf16_t* __restrict__ Wkb,
                                               bf16_t* __restrict__ Wvb,
                                               bf16_t* __restrict__ Wob)
{
    size_t i = ((size_t)blockIdx.x * 256 + threadIdx.x) * 8;
    if (i >= NTOT) return;
    const size_t E0 = NX, E1 = E0 + NWQ, E2 = E1 + NWK, E3 = E2 + NWV;
    const float* s; bf16_t* d; size_t off;
    if (i < E0)      { s = X;  d = Xb;  off = i; }
    else if (i < E1) { s = Wq; d = Wqb; off = i - E0; }
    else if (i < E2) { s = Wk; d = Wkb; off = i - E1; }
    else if (i < E3) { s = Wv; d = Wvb; off = i - E2; }
    else             { s = Wo; d = Wob; off = i - E3; }
    *(bf16x8*)(d + off) = load8(s + off);
}

// ---------------------------------------------------------------------------
// Swizzled-tile convention (T2, both-sides, rule #21):
//   LDS tile = [rows][64] bf16, 128B rows.  Physical 16B slot s of row r
//   holds LOGICAL k-group (s ^ (r&7)).  Staging: linear LDS dest, per-lane
//   pre-swizzled global source.  Reads: slot G ^ (r&7).
//
// XCD swizzle (T1, confirmed R10: qkv 46 -> <40.6us): 1D grid; xcd = bid&7,
// j = bid>>3 indexes a contiguous 2D chunk per XCD so blocks sharing A/B
// panels coalesce in one XCD's L2.
// ---------------------------------------------------------------------------

// ---------------------------------------------------------------------------
// Fused QKV projection + RoPE, 128x128 tiles, 512 threads (8 waves, 4x2
// grid of 32x64 wave-tiles), counted-vmcnt pipeline, XCD-chunked blocks.
// (byte-identical to R10, which passed)
// ---------------------------------------------------------------------------
__global__ __launch_bounds__(512, 4) void qkv_gemm(const bf16_t* __restrict__ Xb,
                                                   const bf16_t* __restrict__ Wqb,
                                                   const bf16_t* __restrict__ Wkb,
                                                   const bf16_t* __restrict__ Wvb,
                                                   bf16_t* __restrict__ Qb,
                                                   bf16_t* __restrict__ Kb,
                                                   bf16_t* __restrict__ Vt)
{
    __shared__ alignas(16) bf16_t sa0[128 * 64], sa1[128 * 64];   // 16KB each
    __shared__ alignas(16) bf16_t sb0[128 * 64], sb1[128 * 64];   // 16KB each
    const int t = threadIdx.x;
    const int lane = t & 63;
    const int w  = t >> 6;               // 0..7
    const int n16 = lane & 15;
    const int q4  = lane >> 4;
    const int wm = (w >> 1) * 32;        // wave tile origin in M (0,32,64,96)
    const int wn = (w & 1) * 64;         // wave tile origin in N (head-aligned)
    f32x4 acc[2][4] = {};

    // ---- T1 XCD-chunked block swizzle: grid 384 = 8 XCDs x (8m x 6n) ----
    const int bid = blockIdx.x;
    const int xcd = bid & 7;
    const int j   = bid >> 3;                    // 0..47
    const int m0 = ((xcd & 1) * 8 + (j & 7)) * 128;     // m-tile 0..15
    const int n0 = ((xcd >> 1) * 6 + (j >> 3)) * 128;   // n-tile 0..23

    const bf16_t* B;
    int mode, nc;
    if (n0 < NH * HD)              { B = Wqb + (size_t)n0 * HID;                     mode = 0; nc = n0; }
    else if (n0 < NH * HD + KVDIM) { B = Wkb + (size_t)(n0 - NH * HD) * HID;         mode = 1; nc = n0 - NH * HD; }
    else                           { B = Wvb + (size_t)(n0 - NH * HD - KVDIM) * HID; mode = 2; nc = n0 - NH * HD - KVDIM; }

    const int lrow8 = lane >> 3;                 // 0..7 (row within 8-row chunk)
    const int lgrp  = (lane & 7) ^ lrow8;        // pre-swizzled source col-group
    const bf16_t* ag = Xb + (size_t)(m0 + w * 16 + lrow8) * HID + lgrp * 8;
    const bf16_t* bg = B  + (size_t)(w * 16 + lrow8) * HID + lgrp * 8;

    auto stage = [&](bf16_t* da, bf16_t* db, int k0) {
        // wave w covers A rows [w*16, w*16+16) and B rows [w*16, w*16+16)
        load_lds16(ag + k0,                      da + (w * 16) * 64);
        load_lds16(ag + (size_t)8 * HID + k0,    da + (w * 16 + 8) * 64);
        load_lds16(bg + k0,                      db + (w * 16) * 64);
        load_lds16(bg + (size_t)8 * HID + k0,    db + (w * 16 + 8) * 64);
    };
    auto mma_step = [&](const bf16_t* sa, const bf16_t* sb) {
#pragma unroll
        for (int kk = 0; kk < 2; ++kk) {
            const int xo = ((kk * 4 + q4) ^ (n16 & 7)) * 8;
            bf16x8 bfrag[4], afrag[2];
#pragma unroll
            for (int j2 = 0; j2 < 4; ++j2)
                bfrag[j2] = *(const bf16x8*)&sb[(wn + j2 * 16 + n16) * 64 + xo];
#pragma unroll
            for (int i = 0; i < 2; ++i)
                afrag[i] = *(const bf16x8*)&sa[(wm + i * 16 + n16) * 64 + xo];
#pragma unroll
            for (int i = 0; i < 2; ++i)
#pragma unroll
                for (int j2 = 0; j2 < 4; ++j2)
                    acc[i][j2] = __builtin_amdgcn_mfma_f32_16x16x32_bf16(afrag[i], bfrag[j2], acc[i][j2], 0, 0, 0);
        }
    };

    // 32 stages of BK=64.  Prologue: stages 0,1.  Loop t issues stage t+2.
    stage(sa0, sb0, 0);
    stage(sa1, sb1, 64);
#pragma unroll 1
    for (int tt = 0; tt < 30; tt += 2) {
        WAITV4;
        mma_step(sa0, sb0);
        BAR;
        stage(sa0, sb0, (tt + 2) * 64);
        WAITV4;
        mma_step(sa1, sb1);
        BAR;
        stage(sa1, sb1, (tt + 3) * 64);
    }
    WAITV4;
    mma_step(sa0, sb0);      // stage 30
    BAR;
    WAITV0;
    mma_step(sa1, sb1);      // stage 31

    if (mode < 2) {
        // ---- RoPE in registers: wave covers one head (wn mult of HD) ----
#pragma unroll
        for (int jt = 0; jt < 2; ++jt) {
            float dd = (float)(jt * 16 + n16);
            float inv = exp2f(-dd * ROPE_L);
#pragma unroll
            for (int i = 0; i < 2; ++i) {
#pragma unroll
                for (int r = 0; r < 4; ++r) {
                    int pos = m0 + wm + i * 16 + q4 * 4 + r;
                    float ang = (float)pos * inv;
                    float sn, cs;
                    sincosf(ang, &sn, &cs);
                    float x1 = acc[i][jt][r], x2 = acc[i][jt + 2][r];
                    acc[i][jt][r]     = x1 * cs - x2 * sn;
                    acc[i][jt + 2][r] = x2 * cs + x1 * sn;
                }
            }
        }
        const float osc = (mode == 0) ? QSCALE : 1.0f;
        bf16_t* dst = (mode == 0) ? Qb : Kb;
        const int ld = (mode == 0) ? NH * HD : KVDIM;
#pragma unroll
        for (int i = 0; i < 2; ++i)
#pragma unroll
            for (int j2 = 0; j2 < 4; ++j2) {
                int row = m0 + wm + i * 16 + q4 * 4;
                int col = nc + wn + j2 * 16 + n16;
#pragma unroll
                for (int r = 0; r < 4; ++r)
                    dst[(size_t)(row + r) * ld + col] = (bf16_t)(acc[i][j2][r] * osc);
            }
    } else {
        // ---- V: store transposed ----
#pragma unroll
        for (int i = 0; i < 2; ++i)
#pragma unroll
            for (int j2 = 0; j2 < 4; ++j2) {
                int row = m0 + wm + i * 16 + q4 * 4;
                int col = nc + wn + j2 * 16 + n16;
#pragma unroll
                for (int r = 0; r < 4; ++r)
                    Vt[(size_t)col * SEQ + row + r] = (bf16_t)acc[i][j2][r];
            }
    }
}

// ---------------------------------------------------------------------------
// O projection: 512-thread 128x128 blocks, grid 256 (1/CU), counted-vmcnt,
// XCD-chunked 8m x 4n blocks.  (byte-identical to R10, which passed)
// ---------------------------------------------------------------------------
__global__ __launch_bounds__(512, 4) void o_gemm(const bf16_t* __restrict__ A,
                                                 const bf16_t* __restrict__ Bw,
                                                 float* __restrict__ C)
{
    __shared__ alignas(16) bf16_t sa0[128 * 64], sa1[128 * 64];
    __shared__ alignas(16) bf16_t sb0[128 * 64], sb1[128 * 64];
    const int t = threadIdx.x;
    const int lane = t & 63;
    const int w  = t >> 6;
    const int n16 = lane & 15;
    const int q4  = lane >> 4;
    const int wm = (w >> 1) * 32;
    const int wn = (w & 1) * 64;
    f32x4 acc[2][4] = {};

    // ---- T1 XCD-chunked swizzle: grid 256 = 8 XCDs x (8m x 4n) ----
    const int bid = blockIdx.x;
    const int xcd = bid & 7;
    const int j   = bid >> 3;                    // 0..31
    const int m0 = ((xcd & 1) * 8 + (j & 7)) * 128;     // m-tile 0..15
    const int n0 = ((xcd >> 1) * 4 + (j >> 3)) * 128;   // n-tile 0..15

    const int lrow8 = lane >> 3;
    const int lgrp  = (lane & 7) ^ lrow8;
    const bf16_t* ag = A  + (size_t)(m0 + w * 16 + lrow8) * HID + lgrp * 8;
    const bf16_t* bg = Bw + (size_t)(n0 + w * 16 + lrow8) * HID + lgrp * 8;

    auto stage = [&](bf16_t* da, bf16_t* db, int k0) {
        load_lds16(ag + k0,                      da + (w * 16) * 64);
        load_lds16(ag + (size_t)8 * HID + k0,    da + (w * 16 + 8) * 64);
        load_lds16(bg + k0,                      db + (w * 16) * 64);
        load_lds16(bg + (size_t)8 * HID + k0,    db + (w * 16 + 8) * 64);
    };
    auto mma_step = [&](const bf16_t* sa, const bf16_t* sb) {
#pragma unroll
        for (int kk = 0; kk < 2; ++kk) {
            const int xo = ((kk * 4 + q4) ^ (n16 & 7)) * 8;
            bf16x8 bfrag[4], afrag[2];
#pragma unroll
            for (int j2 = 0; j2 < 4; ++j2)
                bfrag[j2] = *(const bf16x8*)&sb[(wn + j2 * 16 + n16) * 64 + xo];
#pragma unroll
            for (int i = 0; i < 2; ++i)
                afrag[i] = *(const bf16x8*)&sa[(wm + i * 16 + n16) * 64 + xo];
#pragma unroll
            for (int i = 0; i < 2; ++i)
#pragma unroll
                for (int j2 = 0; j2 < 4; ++j2)
                    acc[i][j2] = __builtin_amdgcn_mfma_f32_16x16x32_bf16(afrag[i], bfrag[j2], acc[i][j2], 0, 0, 0);
        }
    };

    stage(sa0, sb0, 0);
    stage(sa1, sb1, 64);
#pragma unroll 1
    for (int tt = 0; tt < 30; tt += 2) {
        WAITV4;
        mma_step(sa0, sb0);
        BAR;
        stage(sa0, sb0, (tt + 2) * 64);
        WAITV4;
        mma_step(sa1, sb1);
        BAR;
        stage(sa1, sb1, (tt + 3) * 64);
    }
    WAITV4;
    mma_step(sa0, sb0);
    BAR;
    WAITV0;
    mma_step(sa1, sb1);

#pragma unroll
    for (int i = 0; i < 2; ++i)
#pragma unroll
        for (int j2 = 0; j2 < 4; ++j2) {
            int row = m0 + wm + i * 16 + q4 * 4;
            int col = n0 + wn + j2 * 16 + n16;
#pragma unroll
            for (int r = 0; r < 4; ++r)
                C[(size_t)(row + r) * HID + col] = acc[i][j2][r];
        }
}

// ---------------------------------------------------------------------------
// MFMA causal flash attention.  NEW (T12 proper): P never touches LDS.
// After swapped QK^T, lane (n16,q4) holds S[kv=jt*16+q4*4+r][q=n16]; the PV
// A-fragment needs P[q=n16][kv=q4*8+j].  With c[jt][p]=cvt_pk(st[jt][2p],
// st[jt][2p+1]), the needed permutation is an even/odd 16-row deinterleave
// of (c[2h], c[2h+1]):
//   permlane32_swap: {x0x1x2x3},{y0y1y2y3} -> {x0x1y0y1},{x2x3y2y3}
//   permlane16_swap: -> Lo={x0x2y0y2}, Hi={x1x3y1y3}
//   pf[i][h] dwords = [Lo0, Lo1, Hi0, Hi1]   (verified == old LDS mapping)
// Replaces 8 ds_write_b64 + 4 ds_read_b128 + lgkm waits per tile with 16
// VALU permlanes; deletes the 18KB ps buffer -> LDS 32KB -> 4 blocks/CU.
// ---------------------------------------------------------------------------
__global__ __launch_bounds__(256, 4) void attn_mfma(const bf16_t* __restrict__ Qm,
                                                    const bf16_t* __restrict__ Km,
                                                    const bf16_t* __restrict__ Vt,
                                                    bf16_t* __restrict__ Om)
{
    const int bid = blockIdx.x;
    const int h   = bid & (NH - 1);
    const int qt  = (bid < (SEQ / 128) * NH / 2)
                      ? (SEQ / 128 - 1 - (bid >> 5))
                      : ((bid - (SEQ / 128) * NH / 2) >> 5);
    const int q0  = qt * 128;
    const int kvh = h >> 2;            // H/KVH = 4
    const int t    = threadIdx.x;
    const int w    = t >> 6;
    const int lane = t & 63;
    const int n16  = lane & 15;
    const int q4   = lane >> 4;

    __shared__ alignas(16) bf16_t kb0[64 * 64], kb1[64 * 64];   // K: [kv][d] swz, 8KB each
    __shared__ alignas(16) bf16_t vb0[64 * 64], vb1[64 * 64];   // V: [d][kv] swz

    // Q fragments in registers: rows q0 + w*32 + i*16 + n16 (B-layout for swapped QK)
    bf16x8 qf[2][2];
#pragma unroll
    for (int i = 0; i < 2; ++i) {
        const bf16_t* qp = Qm + (size_t)(q0 + w * 32 + i * 16 + n16) * HID + h * HD;
        qf[i][0] = *(const bf16x8*)(qp + q4 * 8);
        qf[i][1] = *(const bf16x8*)(qp + 32 + q4 * 8);
    }

    f32x4 acc[2][4] = {};
    f32x4 acc_l[2] = {};                 // row-sums of P via ones-MFMA
    const bf16_t one = (bf16_t)1.0f;
    const bf16x8 ones8 = {one, one, one, one, one, one, one, one};

    // staging source addresses (pre-swizzled global col-group, T2 rule #21)
    const int lrow8 = lane >> 3;                 // 0..7
    const int lgrp  = (lane & 7) ^ lrow8;        // source 16B group
    const bf16_t* kgs = Km + (size_t)kvh * HD + (size_t)lrow8 * KVDIM + lgrp * 8;
    const bf16_t* vgs = Vt + (size_t)(kvh * HD + lrow8) * SEQ + lgrp * 8;

    // swizzled fragment-read offsets: logical group g at slot g^(r&7)
    const int rx  = n16 & 7;
    const int xo0 = (q4 ^ rx) * 8;               // groups 0..3
    const int xo1 = ((q4 + 4) ^ rx) * 8;         // groups 4..7

    const int ghmax  = 2 * qt + 1;               // last 64-kv tile staged (odd)
    const int my_last = 2 * qt + (w >> 1);       // last 64-kv tile this wave computes

    auto stage = [&](int gh, bf16_t* kb, bf16_t* vb) {
        const int k0 = gh * 64;
        load_lds16(kgs + (size_t)(k0 + w * 8)      * KVDIM, kb + (w * 8)      * 64);
        load_lds16(kgs + (size_t)(k0 + w * 8 + 32) * KVDIM, kb + (w * 8 + 32) * 64);
        load_lds16(vgs + (size_t)(w * 8)      * SEQ + k0,   vb + (w * 8)      * 64);
        load_lds16(vgs + (size_t)(w * 8 + 32) * SEQ + k0,   vb + (w * 8 + 32) * 64);
    };

    auto compute = [&](int gh, const bf16_t* kbuf, const bf16_t* vbuf) {
        // ---- S^T = K Q (swapped): lane holds S[kv = gh*64+jt*16+q4*4+r][q = ..+i*16+n16] ----
        f32x4 st[2][4];
        __builtin_amdgcn_s_setprio(1);
#pragma unroll
        for (int jt = 0; jt < 4; ++jt) {
            bf16x8 kf0 = *(const bf16x8*)&kbuf[(jt * 16 + n16) * 64 + xo0];
            bf16x8 kf1 = *(const bf16x8*)&kbuf[(jt * 16 + n16) * 64 + xo1];
#pragma unroll
            for (int i = 0; i < 2; ++i) {
                f32x4 s = {};
                s = __builtin_amdgcn_mfma_f32_16x16x32_bf16(kf0, qf[i][0], s, 0, 0, 0);
                s = __builtin_amdgcn_mfma_f32_16x16x32_bf16(kf1, qf[i][1], s, 0, 0, 0);
                st[i][jt] = s;
            }
        }
        __builtin_amdgcn_s_setprio(0);

        // ---- causal mask on the diagonal tile (kv > q) ----
        if (gh == my_last) {
#pragma unroll
            for (int i = 0; i < 2; ++i) {
                int qg = q0 + w * 32 + i * 16 + n16;
#pragma unroll
                for (int jt = 0; jt < 4; ++jt) {
                    int kvb = gh * 64 + jt * 16 + q4 * 4;
#pragma unroll
                    for (int r = 0; r < 4; ++r)
                        if (kvb + r > qg) st[i][jt][r] = -1e30f;
                }
            }
        }

        // ---- exp (raw v_exp_f32 path) ----
#pragma unroll
        for (int i = 0; i < 2; ++i)
#pragma unroll
            for (int jt = 0; jt < 4; ++jt)
#pragma unroll
                for (int r = 0; r < 4; ++r)
                    st[i][jt][r] = EXPFN(st[i][jt][r]);

        // ---- P -> PV A-fragments fully in registers (T12) ----
        bf16x8 pf[2][2];
#pragma unroll
        for (int i = 0; i < 2; ++i) {
#pragma unroll
            for (int hh = 0; hh < 2; ++hh) {
                u32x4 pd;
#pragma unroll
                for (int p = 0; p < 2; ++p) {
                    unsigned int x = cvt_pk_bf16(st[i][2 * hh][2 * p],     st[i][2 * hh][2 * p + 1]);
                    unsigned int y = cvt_pk_bf16(st[i][2 * hh + 1][2 * p], st[i][2 * hh + 1][2 * p + 1]);
                    asm("v_permlane32_swap_b32 %0, %1" : "+v"(x), "+v"(y));
                    asm("v_permlane16_swap_b32 %0, %1" : "+v"(x), "+v"(y));
                    pd[p]     = x;   // Lo[p]
                    pd[2 + p] = y;   // Hi[p]
                }
                pf[i][hh] = *(bf16x8*)&pd;
            }
        }

        __builtin_amdgcn_s_setprio(1);
        // ---- l += row-sum(P) via ones-MFMA ----
#pragma unroll
        for (int i = 0; i < 2; ++i) {
            acc_l[i] = __builtin_amdgcn_mfma_f32_16x16x32_bf16(pf[i][0], ones8, acc_l[i], 0, 0, 0);
            acc_l[i] = __builtin_amdgcn_mfma_f32_16x16x32_bf16(pf[i][1], ones8, acc_l[i], 0, 0, 0);
        }
        // ---- O += P V ----
#pragma unroll
        for (int jd = 0; jd < 4; ++jd) {
            bf16x8 vf0 = *(const bf16x8*)&vbuf[(jd * 16 + n16) * 64 + xo0];
            bf16x8 vf1 = *(const bf16x8*)&vbuf[(jd * 16 + n16) * 64 + xo1];
#pragma unroll
            for (int i = 0; i < 2; ++i) {
                acc[i][jd] = __builtin_amdgcn_mfma_f32_16x16x32_bf16(pf[i][0], vf0, acc[i][jd], 0, 0, 0);
                acc[i][jd] = __builtin_amdgcn_mfma_f32_16x16x32_bf16(pf[i][1], vf1, acc[i][jd], 0, 0, 0);
            }
        }
        __builtin_amdgcn_s_setprio(0);
    };

    // ---- 2-phase pipelined main loop (gh-count = 2qt+2, always even) ----
    stage(0, kb0, vb0);
    __syncthreads();
    for (int gh = 0; gh <= ghmax; gh += 2) {
        if (gh < ghmax) stage(gh + 1, kb1, vb1);
        if (gh <= my_last) compute(gh, kb0, vb0);
        __syncthreads();
        if (gh + 1 < ghmax) stage(gh + 2, kb0, vb0);
        if (gh + 1 <= my_last) compute(gh + 1, kb1, vb1);
        __syncthreads();
    }

    // ---- normalize + store ----
#pragma unroll
    for (int i = 0; i < 2; ++i) {
        float linv[4];
#pragma unroll
        for (int r = 0; r < 4; ++r) linv[r] = 1.0f / acc_l[i][r];
#pragma unroll
        for (int jd = 0; jd < 4; ++jd)
#pragma unroll
            for (int r = 0; r < 4; ++r) {
                int rowg = q0 + w * 32 + i * 16 + q4 * 4 + r;
                Om[(size_t)rowg * HID + h * HD + jd * 16 + n16] = (bf16_t)(acc[i][jd][r] * linv[r]);
            }
    }
}

// ---------------------------------------------------------------------------
extern "C" void kernel_launch(void* const* d_in, const int* in_sizes, int n_in,
                              void* d_out, int out_size, void* d_ws, size_t ws_size,
                              hipStream_t stream)
{
    const float* X  = (const float*)d_in[0];
    const float* Wq = (const float*)d_in[1];
    const float* Wk = (const float*)d_in[2];
    const float* Wv = (const float*)d_in[3];
    const float* Wo = (const float*)d_in[4];
    float* out = (float*)d_out;

    bf16_t* Xb  = (bf16_t*)d_ws;                      // [SEQ][HID]     8 MB
    bf16_t* Wqb = Xb  + (size_t)NX;                   // [2048][2048]   8 MB
    bf16_t* Wkb = Wqb + (size_t)NWQ;                  // [512][2048]    2 MB
    bf16_t* Wvb = Wkb + (size_t)NWK;                  // [512][2048]    2 MB
    bf16_t* Wob = Wvb + (size_t)NWV;                  // [2048][2048]   8 MB
    bf16_t* Qb  = Wob + (size_t)NWO;                  // [SEQ][NH*HD]   8 MB (pre-scaled QSCALE)
    bf16_t* Kb  = Qb  + (size_t)SEQ * (NH * HD);      // [SEQ][KVDIM]   2 MB
    bf16_t* Vt  = Kb  + (size_t)SEQ * KVDIM;          // [KVDIM][SEQ]   2 MB
    bf16_t* Ob  = Vt  + (size_t)SEQ * KVDIM;          // [SEQ][NH*HD]   8 MB

    // one-shot fp32 -> bf16 conversion of all operands
    cvt_all<<<dim3((NTOT / 8 + 255) / 256), dim3(256), 0, stream>>>(X, Wq, Wk, Wv, Wo, Xb, Wqb, Wkb, Wvb, Wob);

    // fused QKV projection + RoPE (128x128 tiles, XCD-chunked 1D grid of 384)
    qkv_gemm<<<dim3(16 * 24), dim3(512), 0, stream>>>(Xb, Wqb, Wkb, Wvb, Qb, Kb, Vt);

    // causal GQA attention (Bq=128, 512 blocks, in-register P, 4 blocks/CU)
    attn_mfma<<<dim3((SEQ / 128) * NH), dim3(256), 0, stream>>>(Qb, Kb, Vt, Ob);

    // output projection (128x128 tiles, XCD-chunked 1D grid of 256)
    o_gemm<<<dim3(16 * 16), dim3(512), 0, stream>>>(Ob, Wob, out);
}